// Round 1
// baseline (1045.821 us; speedup 1.0000x reference)
//
#include <hip/hip_runtime.h>
#include <stdint.h>

// Problem constants
#define B_    16
#define C_    80
#define H_    128
#define W_    128
#define HW_   16384        // H_*W_
#define NBINS 1024
#define BIN_BASE 0x3C00u   // float bits>>16 lower bound for scores > ~0.0078
#define SMALL_CAP 8192u
#define SORTN 1024

// ws layout (bytes):
//   hist       : B_*NBINS*4 = 65536   @ 0
//   smallCount : B_*4       = 64      @ 65536
//   threshBin  : B_*4       = 64      @ 65600
//   smallBuf   : B_*SMALL_CAP*8       @ 65664
#define WS_HIST_OFF   0
#define WS_SCNT_OFF   65536
#define WS_TBIN_OFF   65600
#define WS_SBUF_OFF   65664
#define WS_ZERO_BYTES 65664

// ---------------------------------------------------------------------------
// K1: 3x3 NMS + per-batch 1024-bin histogram of score bits
// grid: B_*C_*(H_/16) blocks of 256
// ---------------------------------------------------------------------------
__global__ __launch_bounds__(256) void nms_hist(const float* __restrict__ hm,
                                                unsigned* __restrict__ hist) {
    __shared__ float tile[18 * 128];
    __shared__ unsigned lh[NBINS];
    for (int i = threadIdx.x; i < NBINS; i += 256) lh[i] = 0u;

    int blk = blockIdx.x;
    int rg  = blk & 7;          // row group 0..7
    int bc  = blk >> 3;         // b*C_ + c
    int b   = bc / C_;
    int r0  = rg << 4;

    const float* img = hm + (size_t)bc * HW_;
    for (int i = threadIdx.x; i < 18 * 128; i += 256) {
        int rr = (i >> 7) + r0 - 1;
        tile[i] = (rr >= 0 && rr < H_) ? img[rr * W_ + (i & 127)] : -1.0f;
    }
    __syncthreads();

    for (int p = threadIdx.x; p < 16 * 128; p += 256) {
        int x = p & 127;
        int t = p + 128;             // center in tile
        float v = tile[t];
        if (v <= 0.01f) continue;
        float m = fmaxf(tile[t - 128], tile[t + 128]);
        if (x > 0)
            m = fmaxf(m, fmaxf(tile[t - 129], fmaxf(tile[t - 1], tile[t + 127])));
        if (x < 127)
            m = fmaxf(m, fmaxf(tile[t - 127], fmaxf(tile[t + 1], tile[t + 129])));
        if (v >= m) {
            unsigned bin = (__float_as_uint(v) >> 16) - BIN_BASE;
            if (bin > NBINS - 1) bin = NBINS - 1;
            atomicAdd(&lh[bin], 1u);
        }
    }
    __syncthreads();

    unsigned* gh = hist + (b << 10);
    for (int i = threadIdx.x; i < NBINS; i += 256) {
        unsigned cnt = lh[i];
        if (cnt) atomicAdd(&gh[i], cnt);
    }
}

// ---------------------------------------------------------------------------
// K2: per-batch find smallest bin T with suffix-count >= 100 (else 0)
// grid: B_ blocks of 256
// ---------------------------------------------------------------------------
__global__ __launch_bounds__(256) void find_thresh(const unsigned* __restrict__ hist,
                                                   unsigned* __restrict__ threshBin) {
    int b = blockIdx.x;
    const unsigned* h = hist + (b << 10);
    __shared__ unsigned seg[256];
    int base = threadIdx.x * 4;
    unsigned h0 = h[base], h1 = h[base + 1], h2 = h[base + 2], h3 = h[base + 3];
    seg[threadIdx.x] = h0 + h1 + h2 + h3;
    __syncthreads();
    // inclusive suffix scan over seg
    for (int d = 1; d < 256; d <<= 1) {
        unsigned add = (threadIdx.x + d < 256) ? seg[threadIdx.x + d] : 0u;
        __syncthreads();
        seg[threadIdx.x] += add;
        __syncthreads();
    }
    unsigned mySuf  = seg[threadIdx.x];
    unsigned nextSuf = (threadIdx.x < 255) ? seg[threadIdx.x + 1] : 0u;
    if (threadIdx.x == 0 && mySuf < 100u) threshBin[b] = 0u;   // total < 100: take all
    if (mySuf >= 100u && nextSuf < 100u) {
        unsigned cum = nextSuf;
        int T = base;
        unsigned hv[4] = {h0, h1, h2, h3};
        for (int i = 3; i >= 0; i--) {
            cum += hv[i];
            if (cum >= 100u) { T = base + i; break; }
        }
        threshBin[b] = (unsigned)T;
    }
}

// ---------------------------------------------------------------------------
// K3: NMS again, compact keys with bin >= T into per-batch small buffer
// grid: B_*C_*(H_/16) blocks of 256
// ---------------------------------------------------------------------------
__global__ __launch_bounds__(256) void nms_compact(const float* __restrict__ hm,
                                                   const unsigned* __restrict__ threshBin,
                                                   unsigned* __restrict__ smallCount,
                                                   unsigned long long* __restrict__ smallBuf) {
    __shared__ float tile[18 * 128];
    int blk = blockIdx.x;
    int rg  = blk & 7;
    int bc  = blk >> 3;
    int b   = bc / C_;
    int c   = bc - b * C_;
    int r0  = rg << 4;
    unsigned tb = threshBin[b] + BIN_BASE;

    const float* img = hm + (size_t)bc * HW_;
    for (int i = threadIdx.x; i < 18 * 128; i += 256) {
        int rr = (i >> 7) + r0 - 1;
        tile[i] = (rr >= 0 && rr < H_) ? img[rr * W_ + (i & 127)] : -1.0f;
    }
    __syncthreads();

    for (int p = threadIdx.x; p < 16 * 128; p += 256) {
        int x = p & 127;
        int t = p + 128;
        float v = tile[t];
        if (v <= 0.01f) continue;
        float m = fmaxf(tile[t - 128], tile[t + 128]);
        if (x > 0)
            m = fmaxf(m, fmaxf(tile[t - 129], fmaxf(tile[t - 1], tile[t + 127])));
        if (x < 127)
            m = fmaxf(m, fmaxf(tile[t - 127], fmaxf(tile[t + 1], tile[t + 129])));
        if (v >= m) {
            unsigned bits = __float_as_uint(v);
            if ((bits >> 16) >= tb) {
                int y = r0 + (p >> 7);
                unsigned idx = ((unsigned)c << 14) + ((unsigned)y << 7) + (unsigned)x;
                unsigned pos = atomicAdd(&smallCount[b], 1u);
                if (pos < SMALL_CAP)
                    smallBuf[((unsigned)b << 13) + pos] =
                        ((unsigned long long)bits << 32) |
                        (unsigned long long)(0xFFFFFFFFu - idx);
            }
        }
    }
}

// ---------------------------------------------------------------------------
// K4: per-batch refine (8-bit sub-histogram), compact to <=1024, bitonic sort
// descending, decode + write outputs. grid: B_ blocks of 256
// ---------------------------------------------------------------------------
__global__ __launch_bounds__(256) void topk_decode(const unsigned long long* __restrict__ smallBuf,
                                                   const unsigned* __restrict__ smallCount,
                                                   const unsigned* __restrict__ threshBin,
                                                   const float* __restrict__ offset,
                                                   const float* __restrict__ wh,
                                                   float* __restrict__ out) {
    int b = blockIdx.x;
    __shared__ unsigned sh[256];
    __shared__ unsigned suf[256];
    __shared__ unsigned cntHiSh;
    __shared__ unsigned subThresh;
    __shared__ unsigned cnt2;
    __shared__ unsigned long long s[SORTN];

    unsigned n = smallCount[b];
    if (n > SMALL_CAP) n = SMALL_CAP;
    unsigned tb = threshBin[b] + BIN_BASE;

    sh[threadIdx.x] = 0u;
    if (threadIdx.x == 0) { cntHiSh = 0u; cnt2 = 0u; }
    __syncthreads();

    const unsigned long long* buf = smallBuf + ((unsigned)b << 13);
    // phase 1: sub-histogram of bits[15:8] for keys in bin tb; count keys above tb
    for (unsigned i = threadIdx.x; i < n; i += 256) {
        unsigned bits = (unsigned)(buf[i] >> 32);
        if ((bits >> 16) > tb) atomicAdd(&cntHiSh, 1u);
        else atomicAdd(&sh[(bits >> 8) & 255u], 1u);
    }
    __syncthreads();

    // phase 2: suffix scan to find sub-threshold U
    suf[threadIdx.x] = sh[threadIdx.x];
    __syncthreads();
    for (int d = 1; d < 256; d <<= 1) {
        unsigned add = (threadIdx.x + d < 256) ? suf[threadIdx.x + d] : 0u;
        __syncthreads();
        suf[threadIdx.x] += add;
        __syncthreads();
    }
    unsigned cntHi  = cntHiSh;
    unsigned mySuf  = cntHi + suf[threadIdx.x];
    unsigned nextSuf = cntHi + ((threadIdx.x < 255) ? suf[threadIdx.x + 1] : 0u);
    if (threadIdx.x == 0 && mySuf < 100u) subThresh = 0u;   // n < 100: take all
    if (mySuf >= 100u && nextSuf < 100u) subThresh = (unsigned)threadIdx.x;
    __syncthreads();

    // phase 3: compact qualifying keys into LDS
    unsigned U = subThresh;
    for (unsigned i = threadIdx.x; i < n; i += 256) {
        unsigned long long key = buf[i];
        unsigned bits = (unsigned)(key >> 32);
        bool take = ((bits >> 16) > tb) || (((bits >> 8) & 255u) >= U);
        if (take) {
            unsigned pos = atomicAdd(&cnt2, 1u);
            if (pos < SORTN) s[pos] = key;
        }
    }
    __syncthreads();
    unsigned n2 = cnt2;
    if (n2 > SORTN) n2 = SORTN;
    for (unsigned i = n2 + threadIdx.x; i < SORTN; i += 256) s[i] = 0ull;
    __syncthreads();

    // phase 4: bitonic sort descending (keys > 0 for real candidates, 0 pads sink)
    for (unsigned k = 2; k <= SORTN; k <<= 1) {
        for (unsigned j = k >> 1; j > 0; j >>= 1) {
            for (unsigned t = threadIdx.x; t < SORTN; t += 256) {
                unsigned ixj = t ^ j;
                if (ixj > t) {
                    unsigned long long a = s[t], bb = s[ixj];
                    bool desc = ((t & k) == 0u);
                    if (desc ? (a < bb) : (a > bb)) { s[t] = bb; s[ixj] = a; }
                }
            }
            __syncthreads();
        }
    }

    // phase 5: decode + write
    int r = threadIdx.x;
    if (r < 100) {
        float idv, sc, b0, b1, b2, b3;
        if ((unsigned)r < n2) {
            unsigned long long key = s[r];
            unsigned bits = (unsigned)(key >> 32);
            unsigned idx  = 0xFFFFFFFFu - (unsigned)(key & 0xFFFFFFFFu);
            float v = __uint_as_float(bits);
            int c  = (int)(idx >> 14);
            int sp = (int)(idx & 16383u);
            int y  = sp >> 7;
            int x  = sp & 127;
            const float* offb = offset + (size_t)b * 2 * HW_;
            const float* whb  = wh + (size_t)b * 2 * HW_;
            float ox = offb[sp],        oy = offb[HW_ + sp];
            float ww = whb[sp],         hh = whb[HW_ + sp];
            float cx = (float)x + ox;
            float cy = (float)y + oy;
            idv = (float)c;
            sc  = v;
            b0 = (cx - ww * 0.5f) * 4.0f;
            b1 = (cy - hh * 0.5f) * 4.0f;
            b2 = (cx + ww * 0.5f) * 4.0f;
            b3 = (cy + hh * 0.5f) * 4.0f;
        } else {
            idv = -1.0f; sc = -1.0f;
            b0 = b1 = b2 = b3 = -4.0f;   // where(keep, bbox, -1) * SCALE
        }
        int o = b * 100 + r;
        out[o]         = idv;
        out[1600 + o]  = sc;
        float* bb = out + 3200 + o * 4;
        bb[0] = b0; bb[1] = b1; bb[2] = b2; bb[3] = b3;
    }
}

// ---------------------------------------------------------------------------
extern "C" void kernel_launch(void* const* d_in, const int* in_sizes, int n_in,
                              void* d_out, int out_size, void* d_ws, size_t ws_size,
                              hipStream_t stream) {
    const float* heatmap = (const float*)d_in[0];
    const float* offset  = (const float*)d_in[1];
    const float* wh      = (const float*)d_in[2];
    float* out = (float*)d_out;

    char* ws = (char*)d_ws;
    unsigned* hist       = (unsigned*)(ws + WS_HIST_OFF);
    unsigned* smallCount = (unsigned*)(ws + WS_SCNT_OFF);
    unsigned* threshBin  = (unsigned*)(ws + WS_TBIN_OFF);
    unsigned long long* smallBuf = (unsigned long long*)(ws + WS_SBUF_OFF);

    hipMemsetAsync(d_ws, 0, WS_ZERO_BYTES, stream);

    dim3 blk(256);
    dim3 nmsGrid(B_ * C_ * (H_ / 16));
    nms_hist<<<nmsGrid, blk, 0, stream>>>(heatmap, hist);
    find_thresh<<<dim3(B_), blk, 0, stream>>>(hist, threshBin);
    nms_compact<<<nmsGrid, blk, 0, stream>>>(heatmap, threshBin, smallCount, smallBuf);
    topk_decode<<<dim3(B_), blk, 0, stream>>>(smallBuf, smallCount, threshBin, offset, wh, out);
}

// Round 2
// 277.948 us; speedup vs baseline: 3.7627x; 3.7627x over previous
//
#include <hip/hip_runtime.h>
#include <stdint.h>

// Problem constants
#define B_    16
#define C_    80
#define H_    128
#define W_    128
#define HW_   16384        // H_*W_
#define NBINS 1024
#define BIN_BASE 0x3C00u   // float bits>>16 lower bound for scores > ~0.0078
#define SMALL_CAP 8192u
#define SORTN 1024
#define CNT_STRIDE 64      // pad per-batch counters to 256B (64 u32) apart

// ws layout (bytes):
//   hist       : B_*NBINS*4 = 65536          @ 0
//   smallCount : B_*CNT_STRIDE*4 = 4096      @ 65536   (padded: one counter per 256B)
//   threshBin  : B_*4       = 64             @ 69632
//   smallBuf   : B_*SMALL_CAP*8              @ 69696
#define WS_HIST_OFF   0
#define WS_SCNT_OFF   65536
#define WS_TBIN_OFF   69632
#define WS_SBUF_OFF   69696
#define WS_ZERO_BYTES 69696

// ---------------------------------------------------------------------------
// K1: 3x3 NMS + per-batch 1024-bin histogram of score bits
// grid: B_*C_*(H_/16) blocks of 256
// ---------------------------------------------------------------------------
__global__ __launch_bounds__(256) void nms_hist(const float* __restrict__ hm,
                                                unsigned* __restrict__ hist) {
    __shared__ float tile[18 * 128];
    __shared__ unsigned lh[NBINS];
    for (int i = threadIdx.x; i < NBINS; i += 256) lh[i] = 0u;

    int blk = blockIdx.x;
    int rg  = blk & 7;          // row group 0..7
    int bc  = blk >> 3;         // b*C_ + c
    int b   = bc / C_;
    int r0  = rg << 4;

    const float* img = hm + (size_t)bc * HW_;
    for (int i = threadIdx.x; i < 18 * 128; i += 256) {
        int rr = (i >> 7) + r0 - 1;
        tile[i] = (rr >= 0 && rr < H_) ? img[rr * W_ + (i & 127)] : -1.0f;
    }
    __syncthreads();

    for (int p = threadIdx.x; p < 16 * 128; p += 256) {
        int x = p & 127;
        int t = p + 128;             // center in tile
        float v = tile[t];
        if (v <= 0.01f) continue;
        float m = fmaxf(tile[t - 128], tile[t + 128]);
        if (x > 0)
            m = fmaxf(m, fmaxf(tile[t - 129], fmaxf(tile[t - 1], tile[t + 127])));
        if (x < 127)
            m = fmaxf(m, fmaxf(tile[t - 127], fmaxf(tile[t + 1], tile[t + 129])));
        if (v >= m) {
            unsigned bin = (__float_as_uint(v) >> 16) - BIN_BASE;
            if (bin > NBINS - 1) bin = NBINS - 1;
            atomicAdd(&lh[bin], 1u);
        }
    }
    __syncthreads();

    unsigned* gh = hist + (b << 10);
    for (int i = threadIdx.x; i < NBINS; i += 256) {
        unsigned cnt = lh[i];
        if (cnt) atomicAdd(&gh[i], cnt);
    }
}

// ---------------------------------------------------------------------------
// K2: per-batch find smallest bin T with suffix-count >= 100 (else 0)
// grid: B_ blocks of 256
// ---------------------------------------------------------------------------
__global__ __launch_bounds__(256) void find_thresh(const unsigned* __restrict__ hist,
                                                   unsigned* __restrict__ threshBin) {
    int b = blockIdx.x;
    const unsigned* h = hist + (b << 10);
    __shared__ unsigned seg[256];
    int base = threadIdx.x * 4;
    unsigned h0 = h[base], h1 = h[base + 1], h2 = h[base + 2], h3 = h[base + 3];
    seg[threadIdx.x] = h0 + h1 + h2 + h3;
    __syncthreads();
    // inclusive suffix scan over seg
    for (int d = 1; d < 256; d <<= 1) {
        unsigned add = (threadIdx.x + d < 256) ? seg[threadIdx.x + d] : 0u;
        __syncthreads();
        seg[threadIdx.x] += add;
        __syncthreads();
    }
    unsigned mySuf  = seg[threadIdx.x];
    unsigned nextSuf = (threadIdx.x < 255) ? seg[threadIdx.x + 1] : 0u;
    if (threadIdx.x == 0 && mySuf < 100u) threshBin[b] = 0u;   // total < 100: take all
    if (mySuf >= 100u && nextSuf < 100u) {
        unsigned cum = nextSuf;
        int T = base;
        unsigned hv[4] = {h0, h1, h2, h3};
        for (int i = 3; i >= 0; i--) {
            cum += hv[i];
            if (cum >= 100u) { T = base + i; break; }
        }
        threshBin[b] = (unsigned)T;
    }
}

// ---------------------------------------------------------------------------
// K3: NMS again, compact keys with bin >= T into per-batch small buffer.
// Block-aggregated: LDS candidate list -> ONE global atomic per block to
// reserve a range -> coalesced copy. Counters padded to 256B stride.
// grid: B_*C_*(H_/16) blocks of 256
// ---------------------------------------------------------------------------
__global__ __launch_bounds__(256) void nms_compact(const float* __restrict__ hm,
                                                   const unsigned* __restrict__ threshBin,
                                                   unsigned* __restrict__ smallCount,
                                                   unsigned long long* __restrict__ smallBuf) {
    __shared__ float tile[18 * 128];
    __shared__ unsigned long long lbuf[2048];   // worst case: every pixel a tied max
    __shared__ unsigned lcnt;
    __shared__ unsigned gbase;
    if (threadIdx.x == 0) lcnt = 0u;

    int blk = blockIdx.x;
    int rg  = blk & 7;
    int bc  = blk >> 3;
    int b   = bc / C_;
    int c   = bc - b * C_;
    int r0  = rg << 4;
    unsigned tb = threshBin[b] + BIN_BASE;

    const float* img = hm + (size_t)bc * HW_;
    for (int i = threadIdx.x; i < 18 * 128; i += 256) {
        int rr = (i >> 7) + r0 - 1;
        tile[i] = (rr >= 0 && rr < H_) ? img[rr * W_ + (i & 127)] : -1.0f;
    }
    __syncthreads();

    for (int p = threadIdx.x; p < 16 * 128; p += 256) {
        int x = p & 127;
        int t = p + 128;
        float v = tile[t];
        if (v <= 0.01f) continue;
        float m = fmaxf(tile[t - 128], tile[t + 128]);
        if (x > 0)
            m = fmaxf(m, fmaxf(tile[t - 129], fmaxf(tile[t - 1], tile[t + 127])));
        if (x < 127)
            m = fmaxf(m, fmaxf(tile[t - 127], fmaxf(tile[t + 1], tile[t + 129])));
        if (v >= m) {
            unsigned bits = __float_as_uint(v);
            if ((bits >> 16) >= tb) {
                int y = r0 + (p >> 7);
                unsigned idx = ((unsigned)c << 14) + ((unsigned)y << 7) + (unsigned)x;
                unsigned pos = atomicAdd(&lcnt, 1u);       // LDS atomic — cheap
                lbuf[pos] = ((unsigned long long)bits << 32) |
                            (unsigned long long)(0xFFFFFFFFu - idx);
            }
        }
    }
    __syncthreads();

    unsigned cnt = lcnt;
    if (cnt == 0u) return;
    if (threadIdx.x == 0) gbase = atomicAdd(&smallCount[b * CNT_STRIDE], cnt);
    __syncthreads();
    unsigned base = gbase;
    unsigned long long* dst = smallBuf + ((unsigned)b << 13);
    for (unsigned i = threadIdx.x; i < cnt; i += 256) {
        unsigned pos = base + i;
        if (pos < SMALL_CAP) dst[pos] = lbuf[i];
    }
}

// ---------------------------------------------------------------------------
// K4: per-batch refine (8-bit sub-histogram), compact to <=1024, bitonic sort
// descending, decode + write outputs. grid: B_ blocks of 256
// ---------------------------------------------------------------------------
__global__ __launch_bounds__(256) void topk_decode(const unsigned long long* __restrict__ smallBuf,
                                                   const unsigned* __restrict__ smallCount,
                                                   const unsigned* __restrict__ threshBin,
                                                   const float* __restrict__ offset,
                                                   const float* __restrict__ wh,
                                                   float* __restrict__ out) {
    int b = blockIdx.x;
    __shared__ unsigned sh[256];
    __shared__ unsigned suf[256];
    __shared__ unsigned cntHiSh;
    __shared__ unsigned subThresh;
    __shared__ unsigned cnt2;
    __shared__ unsigned long long s[SORTN];

    unsigned n = smallCount[b * CNT_STRIDE];
    if (n > SMALL_CAP) n = SMALL_CAP;
    unsigned tb = threshBin[b] + BIN_BASE;

    sh[threadIdx.x] = 0u;
    if (threadIdx.x == 0) { cntHiSh = 0u; cnt2 = 0u; }
    __syncthreads();

    const unsigned long long* buf = smallBuf + ((unsigned)b << 13);
    // phase 1: sub-histogram of bits[15:8] for keys in bin tb; count keys above tb
    for (unsigned i = threadIdx.x; i < n; i += 256) {
        unsigned bits = (unsigned)(buf[i] >> 32);
        if ((bits >> 16) > tb) atomicAdd(&cntHiSh, 1u);
        else atomicAdd(&sh[(bits >> 8) & 255u], 1u);
    }
    __syncthreads();

    // phase 2: suffix scan to find sub-threshold U
    suf[threadIdx.x] = sh[threadIdx.x];
    __syncthreads();
    for (int d = 1; d < 256; d <<= 1) {
        unsigned add = (threadIdx.x + d < 256) ? suf[threadIdx.x + d] : 0u;
        __syncthreads();
        suf[threadIdx.x] += add;
        __syncthreads();
    }
    unsigned cntHi  = cntHiSh;
    unsigned mySuf  = cntHi + suf[threadIdx.x];
    unsigned nextSuf = cntHi + ((threadIdx.x < 255) ? suf[threadIdx.x + 1] : 0u);
    if (threadIdx.x == 0 && mySuf < 100u) subThresh = 0u;   // n < 100: take all
    if (mySuf >= 100u && nextSuf < 100u) subThresh = (unsigned)threadIdx.x;
    __syncthreads();

    // phase 3: compact qualifying keys into LDS
    unsigned U = subThresh;
    for (unsigned i = threadIdx.x; i < n; i += 256) {
        unsigned long long key = buf[i];
        unsigned bits = (unsigned)(key >> 32);
        bool take = ((bits >> 16) > tb) || (((bits >> 8) & 255u) >= U);
        if (take) {
            unsigned pos = atomicAdd(&cnt2, 1u);
            if (pos < SORTN) s[pos] = key;
        }
    }
    __syncthreads();
    unsigned n2 = cnt2;
    if (n2 > SORTN) n2 = SORTN;
    for (unsigned i = n2 + threadIdx.x; i < SORTN; i += 256) s[i] = 0ull;
    __syncthreads();

    // phase 4: bitonic sort descending (keys > 0 for real candidates, 0 pads sink)
    for (unsigned k = 2; k <= SORTN; k <<= 1) {
        for (unsigned j = k >> 1; j > 0; j >>= 1) {
            for (unsigned t = threadIdx.x; t < SORTN; t += 256) {
                unsigned ixj = t ^ j;
                if (ixj > t) {
                    unsigned long long a = s[t], bb = s[ixj];
                    bool desc = ((t & k) == 0u);
                    if (desc ? (a < bb) : (a > bb)) { s[t] = bb; s[ixj] = a; }
                }
            }
            __syncthreads();
        }
    }

    // phase 5: decode + write
    int r = threadIdx.x;
    if (r < 100) {
        float idv, sc, b0, b1, b2, b3;
        if ((unsigned)r < n2) {
            unsigned long long key = s[r];
            unsigned bits = (unsigned)(key >> 32);
            unsigned idx  = 0xFFFFFFFFu - (unsigned)(key & 0xFFFFFFFFu);
            float v = __uint_as_float(bits);
            int c  = (int)(idx >> 14);
            int sp = (int)(idx & 16383u);
            int y  = sp >> 7;
            int x  = sp & 127;
            const float* offb = offset + (size_t)b * 2 * HW_;
            const float* whb  = wh + (size_t)b * 2 * HW_;
            float ox = offb[sp],        oy = offb[HW_ + sp];
            float ww = whb[sp],         hh = whb[HW_ + sp];
            float cx = (float)x + ox;
            float cy = (float)y + oy;
            idv = (float)c;
            sc  = v;
            b0 = (cx - ww * 0.5f) * 4.0f;
            b1 = (cy - hh * 0.5f) * 4.0f;
            b2 = (cx + ww * 0.5f) * 4.0f;
            b3 = (cy + hh * 0.5f) * 4.0f;
        } else {
            idv = -1.0f; sc = -1.0f;
            b0 = b1 = b2 = b3 = -4.0f;   // where(keep, bbox, -1) * SCALE
        }
        int o = b * 100 + r;
        out[o]         = idv;
        out[1600 + o]  = sc;
        float* bb = out + 3200 + o * 4;
        bb[0] = b0; bb[1] = b1; bb[2] = b2; bb[3] = b3;
    }
}

// ---------------------------------------------------------------------------
extern "C" void kernel_launch(void* const* d_in, const int* in_sizes, int n_in,
                              void* d_out, int out_size, void* d_ws, size_t ws_size,
                              hipStream_t stream) {
    const float* heatmap = (const float*)d_in[0];
    const float* offset  = (const float*)d_in[1];
    const float* wh      = (const float*)d_in[2];
    float* out = (float*)d_out;

    char* ws = (char*)d_ws;
    unsigned* hist       = (unsigned*)(ws + WS_HIST_OFF);
    unsigned* smallCount = (unsigned*)(ws + WS_SCNT_OFF);
    unsigned* threshBin  = (unsigned*)(ws + WS_TBIN_OFF);
    unsigned long long* smallBuf = (unsigned long long*)(ws + WS_SBUF_OFF);

    hipMemsetAsync(d_ws, 0, WS_ZERO_BYTES, stream);

    dim3 blk(256);
    dim3 nmsGrid(B_ * C_ * (H_ / 16));
    nms_hist<<<nmsGrid, blk, 0, stream>>>(heatmap, hist);
    find_thresh<<<dim3(B_), blk, 0, stream>>>(hist, threshBin);
    nms_compact<<<nmsGrid, blk, 0, stream>>>(heatmap, threshBin, smallCount, smallBuf);
    topk_decode<<<dim3(B_), blk, 0, stream>>>(smallBuf, smallCount, threshBin, offset, wh, out);
}

// Round 3
// 188.126 us; speedup vs baseline: 5.5591x; 1.4775x over previous
//
#include <hip/hip_runtime.h>
#include <stdint.h>

// Problem constants
#define B_    16
#define C_    80
#define H_    128
#define W_    128
#define HW_   16384        // H_*W_
#define NBINS 1024
#define BIN_BASE 0x3C00u   // float bits>>16 lower bound for scores > ~0.0078
#define SMALL_CAP 8192u
#define SORTN 1024
#define CNT_STRIDE 64      // pad per-batch counters to 256B (64 u32) apart
#define F0_BITS 0x3F7F0000u  // 0.99609375f — eager pre-filter (top 1024-bin)

// ws layout (bytes):
//   hist    : B_*NBINS*4 = 65536      @ 0
//   cnt1    : B_*CNT_STRIDE*4 = 4096  @ 65536   (eager counts, padded)
//   cnt2    : B_*CNT_STRIDE*4 = 4096  @ 69632   (fallback counts, padded)
//   fbFlag  : B_*4 = 64               @ 73728
//   threshBin: B_*4 = 64              @ 73792
//   buf     : B_*SMALL_CAP*8 = 1 MB   @ 73856   (shared eager/fallback; fallback
//                                                overwrites from 0 for flagged batches)
#define WS_HIST_OFF 0
#define WS_C1_OFF   65536
#define WS_C2_OFF   69632
#define WS_FLAG_OFF 73728
#define WS_TBIN_OFF 73792
#define WS_BUF_OFF  73856
#define WS_ZERO_BYTES 73856

// ---------------------------------------------------------------------------
// K1: single-pass eager NMS. float4 loads, shuffle x-halo, no LDS tile.
// Candidates (local max AND bits >= F0) -> LDS list -> one global atomic/block.
// grid: B_*C_*(H_/32) = 5120 blocks of 256. Thread = 4 rows x 4 cols.
// ---------------------------------------------------------------------------
__global__ __launch_bounds__(256) void nms_eager(const float* __restrict__ hm,
                                                 unsigned* __restrict__ cnt1,
                                                 unsigned long long* __restrict__ buf) {
    __shared__ unsigned long long lbuf[2048];
    __shared__ unsigned lcnt, gbase;
    if (threadIdx.x == 0) lcnt = 0u;
    __syncthreads();

    int blk = blockIdx.x;
    int rb  = blk & 3;           // 32-row band
    int bc  = blk >> 2;          // b*C_ + c
    int b   = bc / C_;
    int c   = bc - b * C_;
    int tx  = threadIdx.x & 31;  // col group (4 px)
    int ty  = threadIdx.x >> 5;  // row group (4 rows)
    int y0  = rb * 32 + ty * 4;
    int lane = threadIdx.x & 63;

    const float4* img = (const float4*)(hm + (size_t)bc * HW_);

    // rows y0-1 .. y0+4: horizontal 3-max (incl. center) per 4-wide strip
    float4 h[6];
    float4 w1, w2, w3, w4;       // center rows y0..y0+3
    int srcL = (lane > 0) ? lane - 1 : 0;
    int srcR = (lane < 63) ? lane + 1 : 63;
    #pragma unroll
    for (int k = 0; k < 6; k++) {
        int gy = y0 - 1 + k;
        float4 v;
        if (gy >= 0 && gy < H_) v = img[gy * 32 + tx];
        else v = make_float4(-1.f, -1.f, -1.f, -1.f);
        if (k == 1) w1 = v;
        if (k == 2) w2 = v;
        if (k == 3) w3 = v;
        if (k == 4) w4 = v;
        float lft = __shfl(v.w, srcL);
        float rgt = __shfl(v.x, srcR);
        if (tx == 0)  lft = -1.f;
        if (tx == 31) rgt = -1.f;
        h[k].x = fmaxf(v.x, fmaxf(lft, v.y));
        h[k].y = fmaxf(v.y, fmaxf(v.x, v.z));
        h[k].z = fmaxf(v.z, fmaxf(v.y, v.w));
        h[k].w = fmaxf(v.w, fmaxf(v.z, rgt));
    }

    // NMS: v >= max3x3 (max includes v itself -> equivalent to pooled==v)
    float4 ww[4] = {w1, w2, w3, w4};
    #pragma unroll
    for (int r = 0; r < 4; r++) {
        float4 v = ww[r];
        float4 m;
        m.x = fmaxf(h[r].x, fmaxf(h[r + 1].x, h[r + 2].x));
        m.y = fmaxf(h[r].y, fmaxf(h[r + 1].y, h[r + 2].y));
        m.z = fmaxf(h[r].z, fmaxf(h[r + 1].z, h[r + 2].z));
        m.w = fmaxf(h[r].w, fmaxf(h[r + 1].w, h[r + 2].w));
        int y = y0 + r;
        float vv[4] = {v.x, v.y, v.z, v.w};
        float mm[4] = {m.x, m.y, m.z, m.w};
        #pragma unroll
        for (int j = 0; j < 4; j++) {
            float f = vv[j];
            if (f >= mm[j] && __float_as_uint(f) >= F0_BITS) {
                unsigned idx = ((unsigned)c << 14) | ((unsigned)y << 7) |
                               (unsigned)(tx * 4 + j);
                unsigned long long key =
                    ((unsigned long long)__float_as_uint(f) << 32) |
                    (unsigned long long)(0xFFFFFFFFu - idx);
                unsigned pos = atomicAdd(&lcnt, 1u);
                if (pos < 2048u) lbuf[pos] = key;
                else {  // LDS list overflow (pathological ties): spill direct
                    unsigned g = atomicAdd(&cnt1[b * CNT_STRIDE], 1u);
                    if (g < SMALL_CAP) buf[((unsigned)b << 13) + g] = key;
                }
            }
        }
    }
    __syncthreads();

    unsigned cnt = lcnt;
    if (cnt > 2048u) cnt = 2048u;
    if (threadIdx.x == 0 && cnt) gbase = atomicAdd(&cnt1[b * CNT_STRIDE], cnt);
    __syncthreads();
    if (cnt) {
        unsigned base = gbase;
        for (unsigned i = threadIdx.x; i < cnt; i += 256) {
            unsigned p = base + i;
            if (p < SMALL_CAP) buf[((unsigned)b << 13) + p] = lbuf[i];
        }
    }
}

// ---------------------------------------------------------------------------
// K2: per-batch fallback decision. Eager valid iff 100 <= cnt1 <= SMALL_CAP.
// ---------------------------------------------------------------------------
__global__ void set_flags(const unsigned* __restrict__ cnt1,
                          unsigned* __restrict__ fbFlag) {
    int t = threadIdx.x;
    if (t < B_) {
        unsigned n = cnt1[t * CNT_STRIDE];
        fbFlag[t] = (n < 100u || n > SMALL_CAP) ? 1u : 0u;
    }
}

// ---------------------------------------------------------------------------
// Fallback A (flag-gated): 3x3 NMS + per-batch 1024-bin histogram
// grid: B_*C_*(H_/16) blocks of 256
// ---------------------------------------------------------------------------
__global__ __launch_bounds__(256) void nms_hist_fb(const float* __restrict__ hm,
                                                   const unsigned* __restrict__ fbFlag,
                                                   unsigned* __restrict__ hist) {
    int blk = blockIdx.x;
    int rg  = blk & 7;
    int bc  = blk >> 3;
    int b   = bc / C_;
    if (fbFlag[b] == 0u) return;   // eager path succeeded — no work

    __shared__ float tile[18 * 128];
    __shared__ unsigned lh[NBINS];
    for (int i = threadIdx.x; i < NBINS; i += 256) lh[i] = 0u;
    int r0 = rg << 4;

    const float* img = hm + (size_t)bc * HW_;
    for (int i = threadIdx.x; i < 18 * 128; i += 256) {
        int rr = (i >> 7) + r0 - 1;
        tile[i] = (rr >= 0 && rr < H_) ? img[rr * W_ + (i & 127)] : -1.0f;
    }
    __syncthreads();

    for (int p = threadIdx.x; p < 16 * 128; p += 256) {
        int x = p & 127;
        int t = p + 128;
        float v = tile[t];
        if (v <= 0.01f) continue;
        float m = fmaxf(tile[t - 128], tile[t + 128]);
        if (x > 0)
            m = fmaxf(m, fmaxf(tile[t - 129], fmaxf(tile[t - 1], tile[t + 127])));
        if (x < 127)
            m = fmaxf(m, fmaxf(tile[t - 127], fmaxf(tile[t + 1], tile[t + 129])));
        if (v >= m) {
            unsigned bin = (__float_as_uint(v) >> 16) - BIN_BASE;
            if (bin > NBINS - 1) bin = NBINS - 1;
            atomicAdd(&lh[bin], 1u);
        }
    }
    __syncthreads();

    unsigned* gh = hist + (b << 10);
    for (int i = threadIdx.x; i < NBINS; i += 256) {
        unsigned cnt = lh[i];
        if (cnt) atomicAdd(&gh[i], cnt);
    }
}

// ---------------------------------------------------------------------------
// Fallback B: per-batch smallest bin T with suffix >= 100 (hist zero if unused)
// ---------------------------------------------------------------------------
__global__ __launch_bounds__(256) void find_thresh(const unsigned* __restrict__ hist,
                                                   unsigned* __restrict__ threshBin) {
    int b = blockIdx.x;
    const unsigned* h = hist + (b << 10);
    __shared__ unsigned seg[256];
    int base = threadIdx.x * 4;
    unsigned h0 = h[base], h1 = h[base + 1], h2 = h[base + 2], h3 = h[base + 3];
    seg[threadIdx.x] = h0 + h1 + h2 + h3;
    __syncthreads();
    for (int d = 1; d < 256; d <<= 1) {
        unsigned add = (threadIdx.x + d < 256) ? seg[threadIdx.x + d] : 0u;
        __syncthreads();
        seg[threadIdx.x] += add;
        __syncthreads();
    }
    unsigned mySuf  = seg[threadIdx.x];
    unsigned nextSuf = (threadIdx.x < 255) ? seg[threadIdx.x + 1] : 0u;
    if (threadIdx.x == 0 && mySuf < 100u) threshBin[b] = 0u;
    if (mySuf >= 100u && nextSuf < 100u) {
        unsigned cum = nextSuf;
        int T = base;
        unsigned hv[4] = {h0, h1, h2, h3};
        for (int i = 3; i >= 0; i--) {
            cum += hv[i];
            if (cum >= 100u) { T = base + i; break; }
        }
        threshBin[b] = (unsigned)T;
    }
}

// ---------------------------------------------------------------------------
// Fallback C (flag-gated): NMS compact with bin >= T into buf (overwrites the
// abandoned eager entries for this batch), block-aggregated.
// ---------------------------------------------------------------------------
__global__ __launch_bounds__(256) void nms_compact_fb(const float* __restrict__ hm,
                                                      const unsigned* __restrict__ fbFlag,
                                                      const unsigned* __restrict__ threshBin,
                                                      unsigned* __restrict__ cnt2,
                                                      unsigned long long* __restrict__ buf) {
    int blk = blockIdx.x;
    int rg  = blk & 7;
    int bc  = blk >> 3;
    int b   = bc / C_;
    if (fbFlag[b] == 0u) return;

    __shared__ float tile[18 * 128];
    __shared__ unsigned long long lbuf[2048];
    __shared__ unsigned lcnt, gbase;
    if (threadIdx.x == 0) lcnt = 0u;
    int c  = bc - b * C_;
    int r0 = rg << 4;
    unsigned tb = threshBin[b] + BIN_BASE;

    const float* img = hm + (size_t)bc * HW_;
    for (int i = threadIdx.x; i < 18 * 128; i += 256) {
        int rr = (i >> 7) + r0 - 1;
        tile[i] = (rr >= 0 && rr < H_) ? img[rr * W_ + (i & 127)] : -1.0f;
    }
    __syncthreads();

    for (int p = threadIdx.x; p < 16 * 128; p += 256) {
        int x = p & 127;
        int t = p + 128;
        float v = tile[t];
        if (v <= 0.01f) continue;
        float m = fmaxf(tile[t - 128], tile[t + 128]);
        if (x > 0)
            m = fmaxf(m, fmaxf(tile[t - 129], fmaxf(tile[t - 1], tile[t + 127])));
        if (x < 127)
            m = fmaxf(m, fmaxf(tile[t - 127], fmaxf(tile[t + 1], tile[t + 129])));
        if (v >= m) {
            unsigned bits = __float_as_uint(v);
            if ((bits >> 16) >= tb) {
                int y = r0 + (p >> 7);
                unsigned idx = ((unsigned)c << 14) + ((unsigned)y << 7) + (unsigned)x;
                unsigned pos = atomicAdd(&lcnt, 1u);
                if (pos < 2048u)
                    lbuf[pos] = ((unsigned long long)bits << 32) |
                                (unsigned long long)(0xFFFFFFFFu - idx);
            }
        }
    }
    __syncthreads();

    unsigned cnt = lcnt;
    if (cnt > 2048u) cnt = 2048u;
    if (threadIdx.x == 0 && cnt) gbase = atomicAdd(&cnt2[b * CNT_STRIDE], cnt);
    __syncthreads();
    if (cnt) {
        unsigned base = gbase;
        for (unsigned i = threadIdx.x; i < cnt; i += 256) {
            unsigned p = base + i;
            if (p < SMALL_CAP) buf[((unsigned)b << 13) + p] = lbuf[i];
        }
    }
}

// ---------------------------------------------------------------------------
// K4: self-contained per-batch top-100. Local 1024-bin hist -> T1, 256-sub-bin
// refine -> U, compact <=1024, bitonic sort desc, decode + write.
// ---------------------------------------------------------------------------
__global__ __launch_bounds__(256) void topk_decode(const unsigned long long* __restrict__ buf,
                                                   const unsigned* __restrict__ cnt1,
                                                   const unsigned* __restrict__ cnt2,
                                                   const unsigned* __restrict__ fbFlag,
                                                   const float* __restrict__ offset,
                                                   const float* __restrict__ wh,
                                                   float* __restrict__ out) {
    int b = blockIdx.x;
    int t = threadIdx.x;
    __shared__ unsigned lh[NBINS];
    __shared__ unsigned seg[256];
    __shared__ unsigned shC[256];
    __shared__ unsigned sufC[256];
    __shared__ unsigned T1s, cntHiS, Us, cnt2L;
    __shared__ unsigned long long s[SORTN];

    unsigned fb = fbFlag[b];
    unsigned n = fb ? cnt2[b * CNT_STRIDE] : cnt1[b * CNT_STRIDE];
    if (n > SMALL_CAP) n = SMALL_CAP;
    const unsigned long long* mybuf = buf + ((unsigned)b << 13);

    for (int i = t; i < NBINS; i += 256) lh[i] = 0u;
    shC[t] = 0u;
    if (t == 0) { cnt2L = 0u; T1s = 0u; cntHiS = 0u; Us = 0u; }
    __syncthreads();

    // phase A: 1024-bin hist of bits>>16
    for (unsigned i = t; i < n; i += 256) {
        unsigned bits = (unsigned)(mybuf[i] >> 32);
        unsigned bin = (bits >> 16) - BIN_BASE;
        if (bin > NBINS - 1) bin = NBINS - 1;
        atomicAdd(&lh[bin], 1u);
    }
    __syncthreads();

    // phase B: suffix scan -> threshold bin T1, count strictly above = cntHi
    int base4 = t * 4;
    unsigned h0 = lh[base4], h1 = lh[base4 + 1], h2 = lh[base4 + 2], h3 = lh[base4 + 3];
    seg[t] = h0 + h1 + h2 + h3;
    __syncthreads();
    for (int d = 1; d < 256; d <<= 1) {
        unsigned add = (t + d < 256) ? seg[t + d] : 0u;
        __syncthreads();
        seg[t] += add;
        __syncthreads();
    }
    unsigned mySuf = seg[t];
    unsigned nextSuf = (t < 255) ? seg[t + 1] : 0u;
    if (t == 0 && mySuf < 100u) { T1s = 0u; cntHiS = mySuf - h0; }
    if (mySuf >= 100u && nextSuf < 100u) {
        unsigned cum = nextSuf;
        unsigned hv[4] = {h0, h1, h2, h3};
        for (int i = 3; i >= 0; i--) {
            cum += hv[i];
            if (cum >= 100u) { T1s = (unsigned)(base4 + i); cntHiS = cum - hv[i]; break; }
        }
    }
    __syncthreads();
    unsigned T1 = T1s, cntHi = cntHiS;

    // phase C: 256-sub-bin hist of bits[15:8] within bin T1 -> U
    for (unsigned i = t; i < n; i += 256) {
        unsigned bits = (unsigned)(mybuf[i] >> 32);
        unsigned bin = (bits >> 16) - BIN_BASE;
        if (bin > NBINS - 1) bin = NBINS - 1;
        if (bin == T1) atomicAdd(&shC[(bits >> 8) & 255u], 1u);
    }
    __syncthreads();
    sufC[t] = shC[t];
    __syncthreads();
    for (int d = 1; d < 256; d <<= 1) {
        unsigned add = (t + d < 256) ? sufC[t + d] : 0u;
        __syncthreads();
        sufC[t] += add;
        __syncthreads();
    }
    unsigned myS = cntHi + sufC[t];
    unsigned nxS = cntHi + ((t < 255) ? sufC[t + 1] : 0u);
    if (t == 0 && myS < 100u) Us = 0u;
    if (myS >= 100u && nxS < 100u) Us = (unsigned)t;
    __syncthreads();
    unsigned U = Us;

    // phase D: compact qualifying keys
    for (unsigned i = t; i < n; i += 256) {
        unsigned long long key = mybuf[i];
        unsigned bits = (unsigned)(key >> 32);
        unsigned bin = (bits >> 16) - BIN_BASE;
        if (bin > NBINS - 1) bin = NBINS - 1;
        bool take = (bin > T1) || (bin == T1 && ((bits >> 8) & 255u) >= U);
        if (take) {
            unsigned pos = atomicAdd(&cnt2L, 1u);
            if (pos < SORTN) s[pos] = key;
        }
    }
    __syncthreads();
    unsigned n2 = cnt2L;
    if (n2 > SORTN) n2 = SORTN;
    for (unsigned i = n2 + t; i < SORTN; i += 256) s[i] = 0ull;
    __syncthreads();

    // phase E: bitonic sort descending
    for (unsigned k = 2; k <= SORTN; k <<= 1) {
        for (unsigned j = k >> 1; j > 0; j >>= 1) {
            for (unsigned tt = t; tt < SORTN; tt += 256) {
                unsigned ixj = tt ^ j;
                if (ixj > tt) {
                    unsigned long long a = s[tt], bb = s[ixj];
                    bool desc = ((tt & k) == 0u);
                    if (desc ? (a < bb) : (a > bb)) { s[tt] = bb; s[ixj] = a; }
                }
            }
            __syncthreads();
        }
    }

    // phase F: decode + write
    int r = t;
    if (r < 100) {
        float idv, sc, b0, b1, b2, b3;
        if ((unsigned)r < n2) {
            unsigned long long key = s[r];
            unsigned bits = (unsigned)(key >> 32);
            unsigned idx  = 0xFFFFFFFFu - (unsigned)(key & 0xFFFFFFFFu);
            float v = __uint_as_float(bits);
            int c  = (int)(idx >> 14);
            int sp = (int)(idx & 16383u);
            int y  = sp >> 7;
            int x  = sp & 127;
            const float* offb = offset + (size_t)b * 2 * HW_;
            const float* whb  = wh + (size_t)b * 2 * HW_;
            float ox = offb[sp], oy = offb[HW_ + sp];
            float wwv = whb[sp], hh = whb[HW_ + sp];
            float cx = (float)x + ox;
            float cy = (float)y + oy;
            idv = (float)c;
            sc  = v;
            b0 = (cx - wwv * 0.5f) * 4.0f;
            b1 = (cy - hh * 0.5f) * 4.0f;
            b2 = (cx + wwv * 0.5f) * 4.0f;
            b3 = (cy + hh * 0.5f) * 4.0f;
        } else {
            idv = -1.0f; sc = -1.0f;
            b0 = b1 = b2 = b3 = -4.0f;   // where(keep, bbox, -1) * SCALE
        }
        int o = b * 100 + r;
        out[o]        = idv;
        out[1600 + o] = sc;
        float* bb = out + 3200 + o * 4;
        bb[0] = b0; bb[1] = b1; bb[2] = b2; bb[3] = b3;
    }
}

// ---------------------------------------------------------------------------
extern "C" void kernel_launch(void* const* d_in, const int* in_sizes, int n_in,
                              void* d_out, int out_size, void* d_ws, size_t ws_size,
                              hipStream_t stream) {
    const float* heatmap = (const float*)d_in[0];
    const float* offset  = (const float*)d_in[1];
    const float* wh      = (const float*)d_in[2];
    float* out = (float*)d_out;

    char* ws = (char*)d_ws;
    unsigned* hist      = (unsigned*)(ws + WS_HIST_OFF);
    unsigned* cnt1      = (unsigned*)(ws + WS_C1_OFF);
    unsigned* cnt2      = (unsigned*)(ws + WS_C2_OFF);
    unsigned* fbFlag    = (unsigned*)(ws + WS_FLAG_OFF);
    unsigned* threshBin = (unsigned*)(ws + WS_TBIN_OFF);
    unsigned long long* buf = (unsigned long long*)(ws + WS_BUF_OFF);

    hipMemsetAsync(d_ws, 0, WS_ZERO_BYTES, stream);

    nms_eager<<<dim3(B_ * C_ * (H_ / 32)), dim3(256), 0, stream>>>(heatmap, cnt1, buf);
    set_flags<<<dim3(1), dim3(64), 0, stream>>>(cnt1, fbFlag);
    nms_hist_fb<<<dim3(B_ * C_ * (H_ / 16)), dim3(256), 0, stream>>>(heatmap, fbFlag, hist);
    find_thresh<<<dim3(B_), dim3(256), 0, stream>>>(hist, threshBin);
    nms_compact_fb<<<dim3(B_ * C_ * (H_ / 16)), dim3(256), 0, stream>>>(heatmap, fbFlag, threshBin, cnt2, buf);
    topk_decode<<<dim3(B_), dim3(256), 0, stream>>>(buf, cnt1, cnt2, fbFlag, offset, wh, out);
}

// Round 4
// 180.253 us; speedup vs baseline: 5.8020x; 1.0437x over previous
//
#include <hip/hip_runtime.h>
#include <stdint.h>

// Problem constants
#define B_    16
#define C_    80
#define H_    128
#define W_    128
#define HW_   16384        // H_*W_
#define NBINS 1024
#define BIN_BASE 0x3C00u   // float bits>>16 lower bound for scores > ~0.0078
#define SMALL_CAP 8192u
#define SORTN 1024
#define CNT_STRIDE 64      // pad per-batch counters to 256B (64 u32) apart
#define F0_BITS 0x3F7F0000u  // 0.99609375f — eager pre-filter (top 1024-bin)

// ws layout (bytes):
//   hist     : B_*NBINS*4 = 65536     @ 0
//   cnt1     : B_*CNT_STRIDE*4 = 4096 @ 65536   (eager counts, padded)
//   cnt2     : B_*CNT_STRIDE*4 = 4096 @ 69632   (fallback counts, padded)
//   threshBin: B_*4 = 64              @ 73728
//   buf      : B_*SMALL_CAP*8 = 1 MB  @ 73792
#define WS_HIST_OFF 0
#define WS_C1_OFF   65536
#define WS_C2_OFF   69632
#define WS_TBIN_OFF 73728
#define WS_BUF_OFF  73792
#define WS_ZERO_BYTES 73792

// Horizontal 3-max (incl. center) of a 4-wide strip, halo via wave shuffle.
__device__ __forceinline__ float4 hmax3(float4 v, int srcL, int srcR, int tx) {
    float lft = __shfl(v.w, srcL);
    float rgt = __shfl(v.x, srcR);
    if (tx == 0)  lft = -1.f;
    if (tx == 31) rgt = -1.f;
    float4 h;
    h.x = fmaxf(v.x, fmaxf(lft, v.y));
    h.y = fmaxf(v.y, fmaxf(v.x, v.z));
    h.z = fmaxf(v.z, fmaxf(v.y, v.w));
    h.w = fmaxf(v.w, fmaxf(v.z, rgt));
    return h;
}

// ---------------------------------------------------------------------------
// K1: single-pass eager NMS. One block per (b,c) channel; thread = 16 rows x
// 4 cols with rolling 3-row register pipeline. Candidates (local max AND
// bits >= F0) -> LDS list -> one global atomic per block.
// grid: B_*C_ = 1280 blocks of 256.
// ---------------------------------------------------------------------------
__global__ __launch_bounds__(256) void nms_eager(const float* __restrict__ hm,
                                                 unsigned* __restrict__ cnt1,
                                                 unsigned long long* __restrict__ buf) {
    __shared__ unsigned long long lbuf[2048];
    __shared__ unsigned lcnt, gbase;
    if (threadIdx.x == 0) lcnt = 0u;
    __syncthreads();

    int bc = blockIdx.x;         // b*C_ + c
    int b  = bc / C_;
    int c  = bc - b * C_;
    int tx = threadIdx.x & 31;   // col group (4 px)
    int ty = threadIdx.x >> 5;   // row strip (16 rows)
    int y0 = ty << 4;
    int lane = threadIdx.x & 63;
    int srcL = (lane > 0) ? lane - 1 : 0;
    int srcR = (lane < 63) ? lane + 1 : 63;

    const float4* img = (const float4*)(hm + (size_t)bc * HW_);
    const float4 neg1 = make_float4(-1.f, -1.f, -1.f, -1.f);

    float4 r0 = (y0 > 0) ? img[(y0 - 1) * 32 + tx] : neg1;
    float4 hprev = hmax3(r0, srcL, srcR, tx);
    float4 vcur = img[y0 * 32 + tx];
    float4 hcur = hmax3(vcur, srcL, srcR, tx);

    #pragma unroll 4
    for (int i = 0; i < 16; i++) {
        int y = y0 + i;
        float4 vn = (y + 1 < H_) ? img[(y + 1) * 32 + tx] : neg1;
        float4 hnext = hmax3(vn, srcL, srcR, tx);
        float mm[4];
        mm[0] = fmaxf(hprev.x, fmaxf(hcur.x, hnext.x));
        mm[1] = fmaxf(hprev.y, fmaxf(hcur.y, hnext.y));
        mm[2] = fmaxf(hprev.z, fmaxf(hcur.z, hnext.z));
        mm[3] = fmaxf(hprev.w, fmaxf(hcur.w, hnext.w));
        float vv[4] = {vcur.x, vcur.y, vcur.z, vcur.w};
        #pragma unroll
        for (int j = 0; j < 4; j++) {
            float f = vv[j];
            if (f >= mm[j] && __float_as_uint(f) >= F0_BITS) {
                unsigned idx = ((unsigned)c << 14) | ((unsigned)y << 7) |
                               (unsigned)(tx * 4 + j);
                unsigned long long key =
                    ((unsigned long long)__float_as_uint(f) << 32) |
                    (unsigned long long)(0xFFFFFFFFu - idx);
                unsigned pos = atomicAdd(&lcnt, 1u);
                if (pos < 2048u) lbuf[pos] = key;
                else {  // pathological tie overflow: spill direct
                    unsigned g = atomicAdd(&cnt1[b * CNT_STRIDE], 1u);
                    if (g < SMALL_CAP) buf[((unsigned)b << 13) + g] = key;
                }
            }
        }
        hprev = hcur; hcur = hnext; vcur = vn;
    }
    __syncthreads();

    unsigned cnt = lcnt;
    if (cnt > 2048u) cnt = 2048u;
    if (threadIdx.x == 0 && cnt) gbase = atomicAdd(&cnt1[b * CNT_STRIDE], cnt);
    __syncthreads();
    if (cnt) {
        unsigned base = gbase;
        for (unsigned i = threadIdx.x; i < cnt; i += 256) {
            unsigned p = base + i;
            if (p < SMALL_CAP) buf[((unsigned)b << 13) + p] = lbuf[i];
        }
    }
}

// ---------------------------------------------------------------------------
// Fallback A (gated on cnt1): NMS + per-batch 1024-bin histogram.
// Channel-block rolling structure. grid: B_*C_ = 1280 blocks of 256.
// ---------------------------------------------------------------------------
__global__ __launch_bounds__(256) void nms_hist_fb(const float* __restrict__ hm,
                                                   const unsigned* __restrict__ cnt1,
                                                   unsigned* __restrict__ hist) {
    int bc = blockIdx.x;
    int b  = bc / C_;
    unsigned n1 = cnt1[b * CNT_STRIDE];
    if (n1 >= 100u && n1 <= SMALL_CAP) return;   // eager path succeeded

    __shared__ unsigned lh[NBINS];
    for (int i = threadIdx.x; i < NBINS; i += 256) lh[i] = 0u;
    __syncthreads();

    int tx = threadIdx.x & 31;
    int ty = threadIdx.x >> 5;
    int y0 = ty << 4;
    int lane = threadIdx.x & 63;
    int srcL = (lane > 0) ? lane - 1 : 0;
    int srcR = (lane < 63) ? lane + 1 : 63;

    const float4* img = (const float4*)(hm + (size_t)bc * HW_);
    const float4 neg1 = make_float4(-1.f, -1.f, -1.f, -1.f);

    float4 r0 = (y0 > 0) ? img[(y0 - 1) * 32 + tx] : neg1;
    float4 hprev = hmax3(r0, srcL, srcR, tx);
    float4 vcur = img[y0 * 32 + tx];
    float4 hcur = hmax3(vcur, srcL, srcR, tx);

    for (int i = 0; i < 16; i++) {
        int y = y0 + i;
        float4 vn = (y + 1 < H_) ? img[(y + 1) * 32 + tx] : neg1;
        float4 hnext = hmax3(vn, srcL, srcR, tx);
        float mm[4];
        mm[0] = fmaxf(hprev.x, fmaxf(hcur.x, hnext.x));
        mm[1] = fmaxf(hprev.y, fmaxf(hcur.y, hnext.y));
        mm[2] = fmaxf(hprev.z, fmaxf(hcur.z, hnext.z));
        mm[3] = fmaxf(hprev.w, fmaxf(hcur.w, hnext.w));
        float vv[4] = {vcur.x, vcur.y, vcur.z, vcur.w};
        #pragma unroll
        for (int j = 0; j < 4; j++) {
            float f = vv[j];
            if (f > 0.01f && f >= mm[j]) {
                unsigned bin = (__float_as_uint(f) >> 16) - BIN_BASE;
                if (bin > NBINS - 1) bin = NBINS - 1;
                atomicAdd(&lh[bin], 1u);
            }
        }
        hprev = hcur; hcur = hnext; vcur = vn;
    }
    __syncthreads();

    unsigned* gh = hist + (b << 10);
    for (int i = threadIdx.x; i < NBINS; i += 256) {
        unsigned cnt = lh[i];
        if (cnt) atomicAdd(&gh[i], cnt);
    }
}

// ---------------------------------------------------------------------------
// Fallback B (gated): per-batch smallest bin T with suffix >= 100
// ---------------------------------------------------------------------------
__global__ __launch_bounds__(256) void find_thresh(const unsigned* __restrict__ hist,
                                                   const unsigned* __restrict__ cnt1,
                                                   unsigned* __restrict__ threshBin) {
    int b = blockIdx.x;
    unsigned n1 = cnt1[b * CNT_STRIDE];
    if (n1 >= 100u && n1 <= SMALL_CAP) return;

    const unsigned* h = hist + (b << 10);
    __shared__ unsigned seg[256];
    int base = threadIdx.x * 4;
    unsigned h0 = h[base], h1 = h[base + 1], h2 = h[base + 2], h3 = h[base + 3];
    seg[threadIdx.x] = h0 + h1 + h2 + h3;
    __syncthreads();
    for (int d = 1; d < 256; d <<= 1) {
        unsigned add = (threadIdx.x + d < 256) ? seg[threadIdx.x + d] : 0u;
        __syncthreads();
        seg[threadIdx.x] += add;
        __syncthreads();
    }
    unsigned mySuf  = seg[threadIdx.x];
    unsigned nextSuf = (threadIdx.x < 255) ? seg[threadIdx.x + 1] : 0u;
    if (threadIdx.x == 0 && mySuf < 100u) threshBin[b] = 0u;
    if (mySuf >= 100u && nextSuf < 100u) {
        unsigned cum = nextSuf;
        int T = base;
        unsigned hv[4] = {h0, h1, h2, h3};
        for (int i = 3; i >= 0; i--) {
            cum += hv[i];
            if (cum >= 100u) { T = base + i; break; }
        }
        threshBin[b] = (unsigned)T;
    }
}

// ---------------------------------------------------------------------------
// Fallback C (gated): NMS compact with bin >= T into buf (overwrites eager
// entries for this batch). Channel-block rolling. grid: 1280 blocks of 256.
// ---------------------------------------------------------------------------
__global__ __launch_bounds__(256) void nms_compact_fb(const float* __restrict__ hm,
                                                      const unsigned* __restrict__ cnt1,
                                                      const unsigned* __restrict__ threshBin,
                                                      unsigned* __restrict__ cnt2,
                                                      unsigned long long* __restrict__ buf) {
    int bc = blockIdx.x;
    int b  = bc / C_;
    unsigned n1 = cnt1[b * CNT_STRIDE];
    if (n1 >= 100u && n1 <= SMALL_CAP) return;

    __shared__ unsigned long long lbuf[2048];
    __shared__ unsigned lcnt, gbase;
    if (threadIdx.x == 0) lcnt = 0u;
    __syncthreads();

    int c  = bc - b * C_;
    int tx = threadIdx.x & 31;
    int ty = threadIdx.x >> 5;
    int y0 = ty << 4;
    int lane = threadIdx.x & 63;
    int srcL = (lane > 0) ? lane - 1 : 0;
    int srcR = (lane < 63) ? lane + 1 : 63;
    unsigned tb = threshBin[b] + BIN_BASE;

    const float4* img = (const float4*)(hm + (size_t)bc * HW_);
    const float4 neg1 = make_float4(-1.f, -1.f, -1.f, -1.f);

    float4 r0 = (y0 > 0) ? img[(y0 - 1) * 32 + tx] : neg1;
    float4 hprev = hmax3(r0, srcL, srcR, tx);
    float4 vcur = img[y0 * 32 + tx];
    float4 hcur = hmax3(vcur, srcL, srcR, tx);

    for (int i = 0; i < 16; i++) {
        int y = y0 + i;
        float4 vn = (y + 1 < H_) ? img[(y + 1) * 32 + tx] : neg1;
        float4 hnext = hmax3(vn, srcL, srcR, tx);
        float mm[4];
        mm[0] = fmaxf(hprev.x, fmaxf(hcur.x, hnext.x));
        mm[1] = fmaxf(hprev.y, fmaxf(hcur.y, hnext.y));
        mm[2] = fmaxf(hprev.z, fmaxf(hcur.z, hnext.z));
        mm[3] = fmaxf(hprev.w, fmaxf(hcur.w, hnext.w));
        float vv[4] = {vcur.x, vcur.y, vcur.z, vcur.w};
        #pragma unroll
        for (int j = 0; j < 4; j++) {
            float f = vv[j];
            unsigned bits = __float_as_uint(f);
            if (f > 0.01f && f >= mm[j] && (bits >> 16) >= tb) {
                unsigned idx = ((unsigned)c << 14) | ((unsigned)y << 7) |
                               (unsigned)(tx * 4 + j);
                unsigned long long key =
                    ((unsigned long long)bits << 32) |
                    (unsigned long long)(0xFFFFFFFFu - idx);
                unsigned pos = atomicAdd(&lcnt, 1u);
                if (pos < 2048u) lbuf[pos] = key;
                else {
                    unsigned g = atomicAdd(&cnt2[b * CNT_STRIDE], 1u);
                    if (g < SMALL_CAP) buf[((unsigned)b << 13) + g] = key;
                }
            }
        }
        hprev = hcur; hcur = hnext; vcur = vn;
    }
    __syncthreads();

    unsigned cnt = lcnt;
    if (cnt > 2048u) cnt = 2048u;
    if (threadIdx.x == 0 && cnt) gbase = atomicAdd(&cnt2[b * CNT_STRIDE], cnt);
    __syncthreads();
    if (cnt) {
        unsigned base = gbase;
        for (unsigned i = threadIdx.x; i < cnt; i += 256) {
            unsigned p = base + i;
            if (p < SMALL_CAP) buf[((unsigned)b << 13) + p] = lbuf[i];
        }
    }
}

// ---------------------------------------------------------------------------
// K4: self-contained per-batch top-100. Local 1024-bin hist -> T1, 256-sub-bin
// refine -> U, compact <=1024, bitonic sort desc, decode + write.
// ---------------------------------------------------------------------------
__global__ __launch_bounds__(256) void topk_decode(const unsigned long long* __restrict__ buf,
                                                   const unsigned* __restrict__ cnt1,
                                                   const unsigned* __restrict__ cnt2,
                                                   const float* __restrict__ offset,
                                                   const float* __restrict__ wh,
                                                   float* __restrict__ out) {
    int b = blockIdx.x;
    int t = threadIdx.x;
    __shared__ unsigned lh[NBINS];
    __shared__ unsigned seg[256];
    __shared__ unsigned shC[256];
    __shared__ unsigned sufC[256];
    __shared__ unsigned T1s, cntHiS, Us, cnt2L;
    __shared__ unsigned long long s[SORTN];

    unsigned n1 = cnt1[b * CNT_STRIDE];
    bool fb = (n1 < 100u || n1 > SMALL_CAP);
    unsigned n = fb ? cnt2[b * CNT_STRIDE] : n1;
    if (n > SMALL_CAP) n = SMALL_CAP;
    const unsigned long long* mybuf = buf + ((unsigned)b << 13);

    for (int i = t; i < NBINS; i += 256) lh[i] = 0u;
    shC[t] = 0u;
    if (t == 0) { cnt2L = 0u; T1s = 0u; cntHiS = 0u; Us = 0u; }
    __syncthreads();

    // phase A: 1024-bin hist of bits>>16
    for (unsigned i = t; i < n; i += 256) {
        unsigned bits = (unsigned)(mybuf[i] >> 32);
        unsigned bin = (bits >> 16) - BIN_BASE;
        if (bin > NBINS - 1) bin = NBINS - 1;
        atomicAdd(&lh[bin], 1u);
    }
    __syncthreads();

    // phase B: suffix scan -> threshold bin T1, count strictly above = cntHi
    int base4 = t * 4;
    unsigned h0 = lh[base4], h1 = lh[base4 + 1], h2 = lh[base4 + 2], h3 = lh[base4 + 3];
    seg[t] = h0 + h1 + h2 + h3;
    __syncthreads();
    for (int d = 1; d < 256; d <<= 1) {
        unsigned add = (t + d < 256) ? seg[t + d] : 0u;
        __syncthreads();
        seg[t] += add;
        __syncthreads();
    }
    unsigned mySuf = seg[t];
    unsigned nextSuf = (t < 255) ? seg[t + 1] : 0u;
    if (t == 0 && mySuf < 100u) { T1s = 0u; cntHiS = mySuf - h0; }
    if (mySuf >= 100u && nextSuf < 100u) {
        unsigned cum = nextSuf;
        unsigned hv[4] = {h0, h1, h2, h3};
        for (int i = 3; i >= 0; i--) {
            cum += hv[i];
            if (cum >= 100u) { T1s = (unsigned)(base4 + i); cntHiS = cum - hv[i]; break; }
        }
    }
    __syncthreads();
    unsigned T1 = T1s, cntHi = cntHiS;

    // phase C: 256-sub-bin hist of bits[15:8] within bin T1 -> U
    for (unsigned i = t; i < n; i += 256) {
        unsigned bits = (unsigned)(mybuf[i] >> 32);
        unsigned bin = (bits >> 16) - BIN_BASE;
        if (bin > NBINS - 1) bin = NBINS - 1;
        if (bin == T1) atomicAdd(&shC[(bits >> 8) & 255u], 1u);
    }
    __syncthreads();
    sufC[t] = shC[t];
    __syncthreads();
    for (int d = 1; d < 256; d <<= 1) {
        unsigned add = (t + d < 256) ? sufC[t + d] : 0u;
        __syncthreads();
        sufC[t] += add;
        __syncthreads();
    }
    unsigned myS = cntHi + sufC[t];
    unsigned nxS = cntHi + ((t < 255) ? sufC[t + 1] : 0u);
    if (t == 0 && myS < 100u) Us = 0u;
    if (myS >= 100u && nxS < 100u) Us = (unsigned)t;
    __syncthreads();
    unsigned U = Us;

    // phase D: compact qualifying keys
    for (unsigned i = t; i < n; i += 256) {
        unsigned long long key = mybuf[i];
        unsigned bits = (unsigned)(key >> 32);
        unsigned bin = (bits >> 16) - BIN_BASE;
        if (bin > NBINS - 1) bin = NBINS - 1;
        bool take = (bin > T1) || (bin == T1 && ((bits >> 8) & 255u) >= U);
        if (take) {
            unsigned pos = atomicAdd(&cnt2L, 1u);
            if (pos < SORTN) s[pos] = key;
        }
    }
    __syncthreads();
    unsigned n2 = cnt2L;
    if (n2 > SORTN) n2 = SORTN;
    for (unsigned i = n2 + t; i < SORTN; i += 256) s[i] = 0ull;
    __syncthreads();

    // phase E: bitonic sort descending
    for (unsigned k = 2; k <= SORTN; k <<= 1) {
        for (unsigned j = k >> 1; j > 0; j >>= 1) {
            for (unsigned tt = t; tt < SORTN; tt += 256) {
                unsigned ixj = tt ^ j;
                if (ixj > tt) {
                    unsigned long long a = s[tt], bb = s[ixj];
                    bool desc = ((tt & k) == 0u);
                    if (desc ? (a < bb) : (a > bb)) { s[tt] = bb; s[ixj] = a; }
                }
            }
            __syncthreads();
        }
    }

    // phase F: decode + write
    int r = t;
    if (r < 100) {
        float idv, sc, b0, b1, b2, b3;
        if ((unsigned)r < n2) {
            unsigned long long key = s[r];
            unsigned bits = (unsigned)(key >> 32);
            unsigned idx  = 0xFFFFFFFFu - (unsigned)(key & 0xFFFFFFFFu);
            float v = __uint_as_float(bits);
            int c  = (int)(idx >> 14);
            int sp = (int)(idx & 16383u);
            int y  = sp >> 7;
            int x  = sp & 127;
            const float* offb = offset + (size_t)b * 2 * HW_;
            const float* whb  = wh + (size_t)b * 2 * HW_;
            float ox = offb[sp], oy = offb[HW_ + sp];
            float wwv = whb[sp], hh = whb[HW_ + sp];
            float cx = (float)x + ox;
            float cy = (float)y + oy;
            idv = (float)c;
            sc  = v;
            b0 = (cx - wwv * 0.5f) * 4.0f;
            b1 = (cy - hh * 0.5f) * 4.0f;
            b2 = (cx + wwv * 0.5f) * 4.0f;
            b3 = (cy + hh * 0.5f) * 4.0f;
        } else {
            idv = -1.0f; sc = -1.0f;
            b0 = b1 = b2 = b3 = -4.0f;   // where(keep, bbox, -1) * SCALE
        }
        int o = b * 100 + r;
        out[o]        = idv;
        out[1600 + o] = sc;
        float* bb = out + 3200 + o * 4;
        bb[0] = b0; bb[1] = b1; bb[2] = b2; bb[3] = b3;
    }
}

// ---------------------------------------------------------------------------
extern "C" void kernel_launch(void* const* d_in, const int* in_sizes, int n_in,
                              void* d_out, int out_size, void* d_ws, size_t ws_size,
                              hipStream_t stream) {
    const float* heatmap = (const float*)d_in[0];
    const float* offset  = (const float*)d_in[1];
    const float* wh      = (const float*)d_in[2];
    float* out = (float*)d_out;

    char* ws = (char*)d_ws;
    unsigned* hist      = (unsigned*)(ws + WS_HIST_OFF);
    unsigned* cnt1      = (unsigned*)(ws + WS_C1_OFF);
    unsigned* cnt2      = (unsigned*)(ws + WS_C2_OFF);
    unsigned* threshBin = (unsigned*)(ws + WS_TBIN_OFF);
    unsigned long long* buf = (unsigned long long*)(ws + WS_BUF_OFF);

    hipMemsetAsync(d_ws, 0, WS_ZERO_BYTES, stream);

    dim3 blk(256);
    dim3 chanGrid(B_ * C_);
    nms_eager<<<chanGrid, blk, 0, stream>>>(heatmap, cnt1, buf);
    nms_hist_fb<<<chanGrid, blk, 0, stream>>>(heatmap, cnt1, hist);
    find_thresh<<<dim3(B_), blk, 0, stream>>>(hist, cnt1, threshBin);
    nms_compact_fb<<<chanGrid, blk, 0, stream>>>(heatmap, cnt1, threshBin, cnt2, buf);
    topk_decode<<<dim3(B_), blk, 0, stream>>>(buf, cnt1, cnt2, offset, wh, out);
}

// Round 5
// 164.128 us; speedup vs baseline: 6.3720x; 1.0982x over previous
//
#include <hip/hip_runtime.h>
#include <stdint.h>

// Problem constants
#define B_    16
#define C_    80
#define H_    128
#define W_    128
#define HW_   16384        // H_*W_
#define NBINS 1024
#define BIN_BASE 0x3C00u   // float bits>>16 lower bound for scores > ~0.0078
#define SMALL_CAP 8192u
#define SORTN 1024
#define CNT_STRIDE 64      // pad per-batch counters to 256B (64 u32) apart
#define F0_BITS 0x3F7F0000u  // 0.99609375f — eager pre-filter (top 1024-bin)

// ws layout (bytes):
//   hist     : B_*NBINS*4 = 65536     @ 0
//   cnt1     : B_*CNT_STRIDE*4 = 4096 @ 65536   (eager counts, padded)
//   cnt2     : B_*CNT_STRIDE*4 = 4096 @ 69632   (fallback counts, padded)
//   threshBin: B_*4 = 64              @ 73728
//   buf      : B_*SMALL_CAP*8 = 1 MB  @ 73792
#define WS_HIST_OFF 0
#define WS_C1_OFF   65536
#define WS_C2_OFF   69632
#define WS_TBIN_OFF 73728
#define WS_BUF_OFF  73792
#define WS_ZERO_BYTES 73792

// Horizontal 3-max (incl. center) of a 4-wide strip, halo via wave shuffle.
__device__ __forceinline__ float4 hmax3(float4 v, int srcL, int srcR, int tx) {
    float lft = __shfl(v.w, srcL);
    float rgt = __shfl(v.x, srcR);
    if (tx == 0)  lft = -1.f;
    if (tx == 31) rgt = -1.f;
    float4 h;
    h.x = fmaxf(v.x, fmaxf(lft, v.y));
    h.y = fmaxf(v.y, fmaxf(v.x, v.z));
    h.z = fmaxf(v.z, fmaxf(v.y, v.w));
    h.w = fmaxf(v.w, fmaxf(v.z, rgt));
    return h;
}

// Wave-aggregated LDS histogram add: if all valid lanes in the wave share one
// bin (the degenerate near-1.0 case), one atomic per wave instead of 64.
__device__ __forceinline__ void hist_add(unsigned* lh, bool valid, unsigned bin,
                                         int lane) {
    unsigned long long vm = __ballot(valid);
    if (vm == 0ull) return;
    int leader = __ffsll((unsigned long long)vm) - 1;
    unsigned lbin = __shfl(bin, leader);
    unsigned long long sm = __ballot(valid && bin == lbin);
    if (sm == vm) {
        if (lane == leader) atomicAdd(&lh[lbin], (unsigned)__popcll(vm));
    } else if (valid) {
        atomicAdd(&lh[bin], 1u);
    }
}

// ---------------------------------------------------------------------------
// K1: single-pass eager NMS. One block per (b,c) channel; thread = 16 rows x
// 4 cols with rolling 3-row register pipeline. Candidates (local max AND
// bits >= F0) -> LDS list -> one global atomic per block.
// grid: B_*C_ = 1280 blocks of 256.
// ---------------------------------------------------------------------------
__global__ __launch_bounds__(256) void nms_eager(const float* __restrict__ hm,
                                                 unsigned* __restrict__ cnt1,
                                                 unsigned long long* __restrict__ buf) {
    __shared__ unsigned long long lbuf[2048];
    __shared__ unsigned lcnt, gbase;
    if (threadIdx.x == 0) lcnt = 0u;
    __syncthreads();

    int bc = blockIdx.x;         // b*C_ + c
    int b  = bc / C_;
    int c  = bc - b * C_;
    int tx = threadIdx.x & 31;   // col group (4 px)
    int ty = threadIdx.x >> 5;   // row strip (16 rows)
    int y0 = ty << 4;
    int lane = threadIdx.x & 63;
    int srcL = (lane > 0) ? lane - 1 : 0;
    int srcR = (lane < 63) ? lane + 1 : 63;

    const float4* img = (const float4*)(hm + (size_t)bc * HW_);
    const float4 neg1 = make_float4(-1.f, -1.f, -1.f, -1.f);

    float4 r0 = (y0 > 0) ? img[(y0 - 1) * 32 + tx] : neg1;
    float4 hprev = hmax3(r0, srcL, srcR, tx);
    float4 vcur = img[y0 * 32 + tx];
    float4 hcur = hmax3(vcur, srcL, srcR, tx);

    #pragma unroll 4
    for (int i = 0; i < 16; i++) {
        int y = y0 + i;
        float4 vn = (y + 1 < H_) ? img[(y + 1) * 32 + tx] : neg1;
        float4 hnext = hmax3(vn, srcL, srcR, tx);
        float mm[4];
        mm[0] = fmaxf(hprev.x, fmaxf(hcur.x, hnext.x));
        mm[1] = fmaxf(hprev.y, fmaxf(hcur.y, hnext.y));
        mm[2] = fmaxf(hprev.z, fmaxf(hcur.z, hnext.z));
        mm[3] = fmaxf(hprev.w, fmaxf(hcur.w, hnext.w));
        float vv[4] = {vcur.x, vcur.y, vcur.z, vcur.w};
        #pragma unroll
        for (int j = 0; j < 4; j++) {
            float f = vv[j];
            if (f >= mm[j] && __float_as_uint(f) >= F0_BITS) {
                unsigned idx = ((unsigned)c << 14) | ((unsigned)y << 7) |
                               (unsigned)(tx * 4 + j);
                unsigned long long key =
                    ((unsigned long long)__float_as_uint(f) << 32) |
                    (unsigned long long)(0xFFFFFFFFu - idx);
                unsigned pos = atomicAdd(&lcnt, 1u);
                if (pos < 2048u) lbuf[pos] = key;
                else {  // pathological tie overflow: spill direct
                    unsigned g = atomicAdd(&cnt1[b * CNT_STRIDE], 1u);
                    if (g < SMALL_CAP) buf[((unsigned)b << 13) + g] = key;
                }
            }
        }
        hprev = hcur; hcur = hnext; vcur = vn;
    }
    __syncthreads();

    unsigned cnt = lcnt;
    if (cnt > 2048u) cnt = 2048u;
    if (threadIdx.x == 0 && cnt) gbase = atomicAdd(&cnt1[b * CNT_STRIDE], cnt);
    __syncthreads();
    if (cnt) {
        unsigned base = gbase;
        for (unsigned i = threadIdx.x; i < cnt; i += 256) {
            unsigned p = base + i;
            if (p < SMALL_CAP) buf[((unsigned)b << 13) + p] = lbuf[i];
        }
    }
}

// ---------------------------------------------------------------------------
// Fallback A (gated on cnt1): NMS + per-batch 1024-bin histogram.
// Channel-block rolling structure. grid: B_*C_ = 1280 blocks of 256.
// ---------------------------------------------------------------------------
__global__ __launch_bounds__(256) void nms_hist_fb(const float* __restrict__ hm,
                                                   const unsigned* __restrict__ cnt1,
                                                   unsigned* __restrict__ hist) {
    int bc = blockIdx.x;
    int b  = bc / C_;
    unsigned n1 = cnt1[b * CNT_STRIDE];
    if (n1 >= 100u && n1 <= SMALL_CAP) return;   // eager path succeeded

    __shared__ unsigned lh[NBINS];
    for (int i = threadIdx.x; i < NBINS; i += 256) lh[i] = 0u;
    __syncthreads();

    int tx = threadIdx.x & 31;
    int ty = threadIdx.x >> 5;
    int y0 = ty << 4;
    int lane = threadIdx.x & 63;
    int srcL = (lane > 0) ? lane - 1 : 0;
    int srcR = (lane < 63) ? lane + 1 : 63;

    const float4* img = (const float4*)(hm + (size_t)bc * HW_);
    const float4 neg1 = make_float4(-1.f, -1.f, -1.f, -1.f);

    float4 r0 = (y0 > 0) ? img[(y0 - 1) * 32 + tx] : neg1;
    float4 hprev = hmax3(r0, srcL, srcR, tx);
    float4 vcur = img[y0 * 32 + tx];
    float4 hcur = hmax3(vcur, srcL, srcR, tx);

    for (int i = 0; i < 16; i++) {
        int y = y0 + i;
        float4 vn = (y + 1 < H_) ? img[(y + 1) * 32 + tx] : neg1;
        float4 hnext = hmax3(vn, srcL, srcR, tx);
        float mm[4];
        mm[0] = fmaxf(hprev.x, fmaxf(hcur.x, hnext.x));
        mm[1] = fmaxf(hprev.y, fmaxf(hcur.y, hnext.y));
        mm[2] = fmaxf(hprev.z, fmaxf(hcur.z, hnext.z));
        mm[3] = fmaxf(hprev.w, fmaxf(hcur.w, hnext.w));
        float vv[4] = {vcur.x, vcur.y, vcur.z, vcur.w};
        #pragma unroll
        for (int j = 0; j < 4; j++) {
            float f = vv[j];
            bool hit = (f > 0.01f && f >= mm[j]);
            unsigned bin = 0u;
            if (hit) {
                bin = (__float_as_uint(f) >> 16) - BIN_BASE;
                if (bin > NBINS - 1) bin = NBINS - 1;
            }
            hist_add(lh, hit, bin, lane);
        }
        hprev = hcur; hcur = hnext; vcur = vn;
    }
    __syncthreads();

    unsigned* gh = hist + (b << 10);
    for (int i = threadIdx.x; i < NBINS; i += 256) {
        unsigned cnt = lh[i];
        if (cnt) atomicAdd(&gh[i], cnt);
    }
}

// ---------------------------------------------------------------------------
// Fallback B (gated): per-batch smallest bin T with suffix >= 100
// ---------------------------------------------------------------------------
__global__ __launch_bounds__(256) void find_thresh(const unsigned* __restrict__ hist,
                                                   const unsigned* __restrict__ cnt1,
                                                   unsigned* __restrict__ threshBin) {
    int b = blockIdx.x;
    unsigned n1 = cnt1[b * CNT_STRIDE];
    if (n1 >= 100u && n1 <= SMALL_CAP) return;

    const unsigned* h = hist + (b << 10);
    __shared__ unsigned seg[256];
    int base = threadIdx.x * 4;
    unsigned h0 = h[base], h1 = h[base + 1], h2 = h[base + 2], h3 = h[base + 3];
    seg[threadIdx.x] = h0 + h1 + h2 + h3;
    __syncthreads();
    for (int d = 1; d < 256; d <<= 1) {
        unsigned add = (threadIdx.x + d < 256) ? seg[threadIdx.x + d] : 0u;
        __syncthreads();
        seg[threadIdx.x] += add;
        __syncthreads();
    }
    unsigned mySuf  = seg[threadIdx.x];
    unsigned nextSuf = (threadIdx.x < 255) ? seg[threadIdx.x + 1] : 0u;
    if (threadIdx.x == 0 && mySuf < 100u) threshBin[b] = 0u;
    if (mySuf >= 100u && nextSuf < 100u) {
        unsigned cum = nextSuf;
        int T = base;
        unsigned hv[4] = {h0, h1, h2, h3};
        for (int i = 3; i >= 0; i--) {
            cum += hv[i];
            if (cum >= 100u) { T = base + i; break; }
        }
        threshBin[b] = (unsigned)T;
    }
}

// ---------------------------------------------------------------------------
// Fallback C (gated): NMS compact with bin >= T into buf (overwrites eager
// entries for this batch). Channel-block rolling. grid: 1280 blocks of 256.
// ---------------------------------------------------------------------------
__global__ __launch_bounds__(256) void nms_compact_fb(const float* __restrict__ hm,
                                                      const unsigned* __restrict__ cnt1,
                                                      const unsigned* __restrict__ threshBin,
                                                      unsigned* __restrict__ cnt2,
                                                      unsigned long long* __restrict__ buf) {
    int bc = blockIdx.x;
    int b  = bc / C_;
    unsigned n1 = cnt1[b * CNT_STRIDE];
    if (n1 >= 100u && n1 <= SMALL_CAP) return;

    __shared__ unsigned long long lbuf[2048];
    __shared__ unsigned lcnt, gbase;
    if (threadIdx.x == 0) lcnt = 0u;
    __syncthreads();

    int c  = bc - b * C_;
    int tx = threadIdx.x & 31;
    int ty = threadIdx.x >> 5;
    int y0 = ty << 4;
    int lane = threadIdx.x & 63;
    int srcL = (lane > 0) ? lane - 1 : 0;
    int srcR = (lane < 63) ? lane + 1 : 63;
    unsigned tb = threshBin[b] + BIN_BASE;

    const float4* img = (const float4*)(hm + (size_t)bc * HW_);
    const float4 neg1 = make_float4(-1.f, -1.f, -1.f, -1.f);

    float4 r0 = (y0 > 0) ? img[(y0 - 1) * 32 + tx] : neg1;
    float4 hprev = hmax3(r0, srcL, srcR, tx);
    float4 vcur = img[y0 * 32 + tx];
    float4 hcur = hmax3(vcur, srcL, srcR, tx);

    for (int i = 0; i < 16; i++) {
        int y = y0 + i;
        float4 vn = (y + 1 < H_) ? img[(y + 1) * 32 + tx] : neg1;
        float4 hnext = hmax3(vn, srcL, srcR, tx);
        float mm[4];
        mm[0] = fmaxf(hprev.x, fmaxf(hcur.x, hnext.x));
        mm[1] = fmaxf(hprev.y, fmaxf(hcur.y, hnext.y));
        mm[2] = fmaxf(hprev.z, fmaxf(hcur.z, hnext.z));
        mm[3] = fmaxf(hprev.w, fmaxf(hcur.w, hnext.w));
        float vv[4] = {vcur.x, vcur.y, vcur.z, vcur.w};
        #pragma unroll
        for (int j = 0; j < 4; j++) {
            float f = vv[j];
            unsigned bits = __float_as_uint(f);
            if (f > 0.01f && f >= mm[j] && (bits >> 16) >= tb) {
                unsigned idx = ((unsigned)c << 14) | ((unsigned)y << 7) |
                               (unsigned)(tx * 4 + j);
                unsigned long long key =
                    ((unsigned long long)bits << 32) |
                    (unsigned long long)(0xFFFFFFFFu - idx);
                unsigned pos = atomicAdd(&lcnt, 1u);
                if (pos < 2048u) lbuf[pos] = key;
                else {
                    unsigned g = atomicAdd(&cnt2[b * CNT_STRIDE], 1u);
                    if (g < SMALL_CAP) buf[((unsigned)b << 13) + g] = key;
                }
            }
        }
        hprev = hcur; hcur = hnext; vcur = vn;
    }
    __syncthreads();

    unsigned cnt = lcnt;
    if (cnt > 2048u) cnt = 2048u;
    if (threadIdx.x == 0 && cnt) gbase = atomicAdd(&cnt2[b * CNT_STRIDE], cnt);
    __syncthreads();
    if (cnt) {
        unsigned base = gbase;
        for (unsigned i = threadIdx.x; i < cnt; i += 256) {
            unsigned p = base + i;
            if (p < SMALL_CAP) buf[((unsigned)b << 13) + p] = lbuf[i];
        }
    }
}

// ---------------------------------------------------------------------------
// K4: self-contained per-batch top-100. Local 1024-bin hist (wave-aggregated
// atomics) -> T1, 256-sub-bin refine -> U, wave-aggregated compact, adaptive
// bitonic sort desc (256 or 1024), decode + write. grid: B_ blocks of 256.
// ---------------------------------------------------------------------------
__global__ __launch_bounds__(256) void topk_decode(const unsigned long long* __restrict__ buf,
                                                   const unsigned* __restrict__ cnt1,
                                                   const unsigned* __restrict__ cnt2,
                                                   const float* __restrict__ offset,
                                                   const float* __restrict__ wh,
                                                   float* __restrict__ out) {
    int b = blockIdx.x;
    int t = threadIdx.x;
    int lane = t & 63;
    __shared__ unsigned lh[NBINS];
    __shared__ unsigned seg[256];
    __shared__ unsigned shC[256];
    __shared__ unsigned sufC[256];
    __shared__ unsigned T1s, cntHiS, Us, cnt2L;
    __shared__ unsigned long long s[SORTN];

    unsigned n1 = cnt1[b * CNT_STRIDE];
    bool fb = (n1 < 100u || n1 > SMALL_CAP);
    unsigned n = fb ? cnt2[b * CNT_STRIDE] : n1;
    if (n > SMALL_CAP) n = SMALL_CAP;
    const unsigned long long* mybuf = buf + ((unsigned)b << 13);

    for (int i = t; i < NBINS; i += 256) lh[i] = 0u;
    shC[t] = 0u;
    if (t == 0) { cnt2L = 0u; T1s = 0u; cntHiS = 0u; Us = 0u; }
    __syncthreads();

    // phase A: 1024-bin hist of bits>>16, wave-aggregated (degenerate-safe)
    for (unsigned i0 = 0; i0 < n; i0 += 256) {
        unsigned i = i0 + t;
        bool valid = (i < n);
        unsigned bin = 0u;
        if (valid) {
            unsigned bits = (unsigned)(mybuf[i] >> 32);
            bin = (bits >> 16) - BIN_BASE;
            if (bin > NBINS - 1) bin = NBINS - 1;
        }
        hist_add(lh, valid, bin, lane);
    }
    __syncthreads();

    // phase B: suffix scan -> threshold bin T1, count strictly above = cntHi
    int base4 = t * 4;
    unsigned h0 = lh[base4], h1 = lh[base4 + 1], h2 = lh[base4 + 2], h3 = lh[base4 + 3];
    seg[t] = h0 + h1 + h2 + h3;
    __syncthreads();
    for (int d = 1; d < 256; d <<= 1) {
        unsigned add = (t + d < 256) ? seg[t + d] : 0u;
        __syncthreads();
        seg[t] += add;
        __syncthreads();
    }
    unsigned mySuf = seg[t];
    unsigned nextSuf = (t < 255) ? seg[t + 1] : 0u;
    if (t == 0 && mySuf < 100u) { T1s = 0u; cntHiS = mySuf - h0; }
    if (mySuf >= 100u && nextSuf < 100u) {
        unsigned cum = nextSuf;
        unsigned hv[4] = {h0, h1, h2, h3};
        for (int i = 3; i >= 0; i--) {
            cum += hv[i];
            if (cum >= 100u) { T1s = (unsigned)(base4 + i); cntHiS = cum - hv[i]; break; }
        }
    }
    __syncthreads();
    unsigned T1 = T1s, cntHi = cntHiS;

    // phase C: 256-sub-bin hist of bits[15:8] within bin T1 -> U (spread bins)
    for (unsigned i = t; i < n; i += 256) {
        unsigned bits = (unsigned)(mybuf[i] >> 32);
        unsigned bin = (bits >> 16) - BIN_BASE;
        if (bin > NBINS - 1) bin = NBINS - 1;
        if (bin == T1) atomicAdd(&shC[(bits >> 8) & 255u], 1u);
    }
    __syncthreads();
    sufC[t] = shC[t];
    __syncthreads();
    for (int d = 1; d < 256; d <<= 1) {
        unsigned add = (t + d < 256) ? sufC[t + d] : 0u;
        __syncthreads();
        sufC[t] += add;
        __syncthreads();
    }
    unsigned myS = cntHi + sufC[t];
    unsigned nxS = cntHi + ((t < 255) ? sufC[t + 1] : 0u);
    if (t == 0 && myS < 100u) Us = 0u;
    if (myS >= 100u && nxS < 100u) Us = (unsigned)t;
    __syncthreads();
    unsigned U = Us;

    // phase D: wave-aggregated compaction of qualifying keys into LDS
    for (unsigned i0 = 0; i0 < n; i0 += 256) {
        unsigned i = i0 + t;
        bool valid = (i < n);
        unsigned long long key = valid ? mybuf[i] : 0ull;
        bool take = false;
        if (valid) {
            unsigned bits = (unsigned)(key >> 32);
            unsigned bin = (bits >> 16) - BIN_BASE;
            if (bin > NBINS - 1) bin = NBINS - 1;
            take = (bin > T1) || (bin == T1 && ((bits >> 8) & 255u) >= U);
        }
        unsigned long long m = __ballot(take);
        if (m != 0ull) {
            int leader = __ffsll((unsigned long long)m) - 1;
            unsigned wcnt = (unsigned)__popcll(m);
            unsigned wbase = 0u;
            if (lane == leader) wbase = atomicAdd(&cnt2L, wcnt);
            wbase = __shfl(wbase, leader);
            if (take) {
                unsigned prefix = (unsigned)__popcll(m & ((1ull << lane) - 1ull));
                unsigned pos = wbase + prefix;
                if (pos < SORTN) s[pos] = key;
            }
        }
    }
    __syncthreads();
    unsigned n2 = cnt2L;
    if (n2 > SORTN) n2 = SORTN;

    // phase E: adaptive bitonic sort descending (pads 0 sink to the bottom)
    unsigned SN = (n2 <= 256u) ? 256u : SORTN;
    for (unsigned i = n2 + t; i < SN; i += 256) s[i] = 0ull;
    __syncthreads();
    for (unsigned k = 2; k <= SN; k <<= 1) {
        for (unsigned j = k >> 1; j > 0; j >>= 1) {
            for (unsigned tt = t; tt < SN; tt += 256) {
                unsigned ixj = tt ^ j;
                if (ixj > tt) {
                    unsigned long long a = s[tt], bb = s[ixj];
                    bool desc = ((tt & k) == 0u);
                    if (desc ? (a < bb) : (a > bb)) { s[tt] = bb; s[ixj] = a; }
                }
            }
            __syncthreads();
        }
    }

    // phase F: decode + write
    int r = t;
    if (r < 100) {
        float idv, sc, b0, b1, b2, b3;
        if ((unsigned)r < n2) {
            unsigned long long key = s[r];
            unsigned bits = (unsigned)(key >> 32);
            unsigned idx  = 0xFFFFFFFFu - (unsigned)(key & 0xFFFFFFFFu);
            float v = __uint_as_float(bits);
            int c  = (int)(idx >> 14);
            int sp = (int)(idx & 16383u);
            int y  = sp >> 7;
            int x  = sp & 127;
            const float* offb = offset + (size_t)b * 2 * HW_;
            const float* whb  = wh + (size_t)b * 2 * HW_;
            float ox = offb[sp], oy = offb[HW_ + sp];
            float wwv = whb[sp], hh = whb[HW_ + sp];
            float cx = (float)x + ox;
            float cy = (float)y + oy;
            idv = (float)c;
            sc  = v;
            b0 = (cx - wwv * 0.5f) * 4.0f;
            b1 = (cy - hh * 0.5f) * 4.0f;
            b2 = (cx + wwv * 0.5f) * 4.0f;
            b3 = (cy + hh * 0.5f) * 4.0f;
        } else {
            idv = -1.0f; sc = -1.0f;
            b0 = b1 = b2 = b3 = -4.0f;   // where(keep, bbox, -1) * SCALE
        }
        int o = b * 100 + r;
        out[o]        = idv;
        out[1600 + o] = sc;
        float* bb = out + 3200 + o * 4;
        bb[0] = b0; bb[1] = b1; bb[2] = b2; bb[3] = b3;
    }
}

// ---------------------------------------------------------------------------
extern "C" void kernel_launch(void* const* d_in, const int* in_sizes, int n_in,
                              void* d_out, int out_size, void* d_ws, size_t ws_size,
                              hipStream_t stream) {
    const float* heatmap = (const float*)d_in[0];
    const float* offset  = (const float*)d_in[1];
    const float* wh      = (const float*)d_in[2];
    float* out = (float*)d_out;

    char* ws = (char*)d_ws;
    unsigned* hist      = (unsigned*)(ws + WS_HIST_OFF);
    unsigned* cnt1      = (unsigned*)(ws + WS_C1_OFF);
    unsigned* cnt2      = (unsigned*)(ws + WS_C2_OFF);
    unsigned* threshBin = (unsigned*)(ws + WS_TBIN_OFF);
    unsigned long long* buf = (unsigned long long*)(ws + WS_BUF_OFF);

    hipMemsetAsync(d_ws, 0, WS_ZERO_BYTES, stream);

    dim3 blk(256);
    dim3 chanGrid(B_ * C_);
    nms_eager<<<chanGrid, blk, 0, stream>>>(heatmap, cnt1, buf);
    nms_hist_fb<<<chanGrid, blk, 0, stream>>>(heatmap, cnt1, hist);
    find_thresh<<<dim3(B_), blk, 0, stream>>>(hist, cnt1, threshBin);
    nms_compact_fb<<<chanGrid, blk, 0, stream>>>(heatmap, cnt1, threshBin, cnt2, buf);
    topk_decode<<<dim3(B_), blk, 0, stream>>>(buf, cnt1, cnt2, offset, wh, out);
}

// Round 6
// 158.039 us; speedup vs baseline: 6.6175x; 1.0385x over previous
//
#include <hip/hip_runtime.h>
#include <stdint.h>

// Problem constants
#define B_    16
#define C_    80
#define H_    128
#define W_    128
#define HW_   16384        // H_*W_
#define NBINS 1024
#define BIN_BASE 0x3C00u   // float bits>>16 lower bound for scores > ~0.0078
#define SMALL_CAP 8192u
#define SORTN 1024
#define CNT_STRIDE 64      // pad per-batch counters to 256B (64 u32) apart
#define F0_BITS 0x3F7F0000u  // 0.99609375f — eager pre-filter (top 1024-bin)

// ws layout (bytes):
//   cnt1 : B_*CNT_STRIDE*4 = 4096 @ 0      (eager counts, padded, pre-zeroed)
//   buf  : B_*SMALL_CAP*8 = 1 MB  @ 4096
#define WS_C1_OFF  0
#define WS_BUF_OFF 4096
#define WS_ZERO_BYTES 4096

// Horizontal 3-max (incl. center) of a 4-wide strip, halo via wave shuffle.
__device__ __forceinline__ float4 hmax3(float4 v, int srcL, int srcR, int tx) {
    float lft = __shfl(v.w, srcL);
    float rgt = __shfl(v.x, srcR);
    if (tx == 0)  lft = -1.f;
    if (tx == 31) rgt = -1.f;
    float4 h;
    h.x = fmaxf(v.x, fmaxf(lft, v.y));
    h.y = fmaxf(v.y, fmaxf(v.x, v.z));
    h.z = fmaxf(v.z, fmaxf(v.y, v.w));
    h.w = fmaxf(v.w, fmaxf(v.z, rgt));
    return h;
}

// Wave-aggregated LDS histogram add: if all valid lanes in the wave share one
// bin (the degenerate near-1.0 case), one atomic per wave instead of 64.
__device__ __forceinline__ void hist_add(unsigned* lh, bool valid, unsigned bin,
                                         int lane) {
    unsigned long long vm = __ballot(valid);
    if (vm == 0ull) return;
    int leader = __ffsll((unsigned long long)vm) - 1;
    unsigned lbin = __shfl(bin, leader);
    unsigned long long sm = __ballot(valid && bin == lbin);
    if (sm == vm) {
        if (lane == leader) atomicAdd(&lh[lbin], (unsigned)__popcll(vm));
    } else if (valid) {
        atomicAdd(&lh[bin], 1u);
    }
}

__device__ __forceinline__ unsigned long long make_key(unsigned bits, int c,
                                                       int y, int x) {
    unsigned idx = ((unsigned)c << 14) | ((unsigned)y << 7) | (unsigned)x;
    return ((unsigned long long)bits << 32) |
           (unsigned long long)(0xFFFFFFFFu - idx);
}

// Rolling 3-row NMS scan of one 128x128 channel by a 256-thread block.
// emit(f, m3x3, y, x) is invoked for ALL 16x4 pixels of each thread
// (unconditionally — safe for wave-ballot inside emit).
template <typename EmitFn>
__device__ __forceinline__ void nms_scan_channel(const float4* __restrict__ img,
                                                 EmitFn emit) {
    int tx = threadIdx.x & 31;   // col group (4 px)
    int ty = threadIdx.x >> 5;   // row strip (16 rows)
    int y0 = ty << 4;
    int lane = threadIdx.x & 63;
    int srcL = (lane > 0) ? lane - 1 : 0;
    int srcR = (lane < 63) ? lane + 1 : 63;
    const float4 neg1 = make_float4(-1.f, -1.f, -1.f, -1.f);

    float4 r0 = (y0 > 0) ? img[(y0 - 1) * 32 + tx] : neg1;
    float4 hprev = hmax3(r0, srcL, srcR, tx);
    float4 vcur = img[y0 * 32 + tx];
    float4 hcur = hmax3(vcur, srcL, srcR, tx);

    #pragma unroll 4
    for (int i = 0; i < 16; i++) {
        int y = y0 + i;
        float4 vn = (y + 1 < H_) ? img[(y + 1) * 32 + tx] : neg1;
        float4 hnext = hmax3(vn, srcL, srcR, tx);
        float mm[4];
        mm[0] = fmaxf(hprev.x, fmaxf(hcur.x, hnext.x));
        mm[1] = fmaxf(hprev.y, fmaxf(hcur.y, hnext.y));
        mm[2] = fmaxf(hprev.z, fmaxf(hcur.z, hnext.z));
        mm[3] = fmaxf(hprev.w, fmaxf(hcur.w, hnext.w));
        float vv[4] = {vcur.x, vcur.y, vcur.z, vcur.w};
        #pragma unroll
        for (int j = 0; j < 4; j++) emit(vv[j], mm[j], y, tx * 4 + j);
        hprev = hcur; hcur = hnext; vcur = vn;
    }
}

// 1024-bin suffix threshold: T = smallest bin with suffix-count >= 100 (0 if
// total < 100); cntHi = count strictly above T. All 256 threads participate.
__device__ __forceinline__ void find_suffix_thresh(const unsigned* __restrict__ h,
                                                   unsigned* __restrict__ seg,
                                                   unsigned* Tout,
                                                   unsigned* cntHiOut) {
    __syncthreads();   // make prior hist atomics visible
    int t = threadIdx.x;
    int base = t * 4;
    unsigned h0 = h[base], h1 = h[base + 1], h2 = h[base + 2], h3 = h[base + 3];
    seg[t] = h0 + h1 + h2 + h3;
    __syncthreads();
    for (int d = 1; d < 256; d <<= 1) {
        unsigned add = (t + d < 256) ? seg[t + d] : 0u;
        __syncthreads();
        seg[t] += add;
        __syncthreads();
    }
    unsigned mySuf = seg[t];
    unsigned nextSuf = (t < 255) ? seg[t + 1] : 0u;
    if (t == 0 && mySuf < 100u) { *Tout = 0u; *cntHiOut = mySuf - h0; }
    if (mySuf >= 100u && nextSuf < 100u) {
        unsigned cum = nextSuf;
        unsigned hv[4] = {h0, h1, h2, h3};
        for (int i = 3; i >= 0; i--) {
            cum += hv[i];
            if (cum >= 100u) { *Tout = (unsigned)(base + i); *cntHiOut = cum - hv[i]; break; }
        }
    }
    __syncthreads();
}

// ---------------------------------------------------------------------------
// K1: single-pass eager NMS. One block per (b,c) channel. Candidates (local
// max AND bits >= F0) -> LDS list -> one global atomic per block.
// grid: B_*C_ = 1280 blocks of 256.
// ---------------------------------------------------------------------------
__global__ __launch_bounds__(256) void nms_eager(const float* __restrict__ hm,
                                                 unsigned* __restrict__ cnt1,
                                                 unsigned long long* __restrict__ buf) {
    __shared__ unsigned long long lbuf[2048];
    __shared__ unsigned lcnt, gbase;
    if (threadIdx.x == 0) lcnt = 0u;
    __syncthreads();

    int bc = blockIdx.x;         // b*C_ + c
    int b  = bc / C_;
    int c  = bc - b * C_;
    const float4* img = (const float4*)(hm + (size_t)bc * HW_);

    nms_scan_channel(img, [&](float f, float m, int y, int x) {
        if (f >= m && __float_as_uint(f) >= F0_BITS) {
            unsigned long long key = make_key(__float_as_uint(f), c, y, x);
            unsigned pos = atomicAdd(&lcnt, 1u);
            if (pos < 2048u) lbuf[pos] = key;
            else {  // pathological tie overflow: spill direct
                unsigned g = atomicAdd(&cnt1[b * CNT_STRIDE], 1u);
                if (g < SMALL_CAP) buf[((unsigned)b << 13) + g] = key;
            }
        }
    });
    __syncthreads();

    unsigned cnt = lcnt;
    if (cnt > 2048u) cnt = 2048u;
    if (threadIdx.x == 0 && cnt) gbase = atomicAdd(&cnt1[b * CNT_STRIDE], cnt);
    __syncthreads();
    if (cnt) {
        unsigned base = gbase;
        for (unsigned i = threadIdx.x; i < cnt; i += 256) {
            unsigned p = base + i;
            if (p < SMALL_CAP) buf[((unsigned)b << 13) + p] = lbuf[i];
        }
    }
}

// ---------------------------------------------------------------------------
// K2: per-batch top-100 with integrated fallback. Normal path: refine the
// eager candidate buffer (hist -> T1, sub-hist -> U, compact). Fallback path
// (cnt1 out of [100, SMALL_CAP]): this block re-scans the batch's 80 channels
// directly (3 passes) — slow but only on pathological data. Then adaptive
// bitonic sort desc + decode + write. grid: B_ blocks of 256.
// ---------------------------------------------------------------------------
__global__ __launch_bounds__(256) void topk_decode(const float* __restrict__ hm,
                                                   const unsigned long long* __restrict__ buf,
                                                   const unsigned* __restrict__ cnt1,
                                                   const float* __restrict__ offset,
                                                   const float* __restrict__ wh,
                                                   float* __restrict__ out) {
    int b = blockIdx.x;
    int t = threadIdx.x;
    int lane = t & 63;
    __shared__ unsigned lh[NBINS];
    __shared__ unsigned seg[256];
    __shared__ unsigned shC[256];
    __shared__ unsigned sufC[256];
    __shared__ unsigned T1s, cntHiS, Us, cntL;
    __shared__ unsigned long long s[SORTN];

    unsigned n1 = cnt1[b * CNT_STRIDE];
    bool fb = (n1 < 100u || n1 > SMALL_CAP);
    const unsigned long long* mybuf = buf + ((unsigned)b << 13);

    for (int i = t; i < NBINS; i += 256) lh[i] = 0u;
    shC[t] = 0u;
    if (t == 0) { cntL = 0u; T1s = 0u; cntHiS = 0u; Us = 0u; }
    __syncthreads();

    unsigned n2;
    if (!fb) {
        unsigned n = n1;
        // phase A: 1024-bin hist of bits>>16, wave-aggregated
        for (unsigned i0 = 0; i0 < n; i0 += 256) {
            unsigned i = i0 + t;
            bool valid = (i < n);
            unsigned bin = 0u;
            if (valid) {
                unsigned bits = (unsigned)(mybuf[i] >> 32);
                bin = (bits >> 16) - BIN_BASE;
                if (bin > NBINS - 1) bin = NBINS - 1;
            }
            hist_add(lh, valid, bin, lane);
        }
        // phase B: threshold bin T1, count strictly above = cntHi
        find_suffix_thresh(lh, seg, &T1s, &cntHiS);
        unsigned T1 = T1s, cntHi = cntHiS;

        // phase C: 256-sub-bin hist of bits[15:8] within bin T1 -> U
        for (unsigned i = t; i < n; i += 256) {
            unsigned bits = (unsigned)(mybuf[i] >> 32);
            unsigned bin = (bits >> 16) - BIN_BASE;
            if (bin > NBINS - 1) bin = NBINS - 1;
            if (bin == T1) atomicAdd(&shC[(bits >> 8) & 255u], 1u);
        }
        __syncthreads();
        sufC[t] = shC[t];
        __syncthreads();
        for (int d = 1; d < 256; d <<= 1) {
            unsigned add = (t + d < 256) ? sufC[t + d] : 0u;
            __syncthreads();
            sufC[t] += add;
            __syncthreads();
        }
        unsigned myS = cntHi + sufC[t];
        unsigned nxS = cntHi + ((t < 255) ? sufC[t + 1] : 0u);
        if (t == 0 && myS < 100u) Us = 0u;
        if (myS >= 100u && nxS < 100u) Us = (unsigned)t;
        __syncthreads();
        unsigned U = Us;

        // phase D: wave-aggregated compaction of qualifying keys into LDS
        for (unsigned i0 = 0; i0 < n; i0 += 256) {
            unsigned i = i0 + t;
            bool valid = (i < n);
            unsigned long long key = valid ? mybuf[i] : 0ull;
            bool take = false;
            if (valid) {
                unsigned bits = (unsigned)(key >> 32);
                unsigned bin = (bits >> 16) - BIN_BASE;
                if (bin > NBINS - 1) bin = NBINS - 1;
                take = (bin > T1) || (bin == T1 && ((bits >> 8) & 255u) >= U);
            }
            unsigned long long m = __ballot(take);
            if (m != 0ull) {
                int leader = __ffsll((unsigned long long)m) - 1;
                unsigned wcnt = (unsigned)__popcll(m);
                unsigned wbase = 0u;
                if (lane == leader) wbase = atomicAdd(&cntL, wcnt);
                wbase = __shfl(wbase, leader);
                if (take) {
                    unsigned prefix = (unsigned)__popcll(m & ((1ull << lane) - 1ull));
                    unsigned pos = wbase + prefix;
                    if (pos < SORTN) s[pos] = key;
                }
            }
        }
        __syncthreads();
        n2 = cntL;
    } else {
        // ---- fallback: in-block exact re-scan of this batch's 80 channels
        // pass 1: 1024-bin hist over all local maxima with f > 0.01
        for (int c = 0; c < C_; c++) {
            const float4* img = (const float4*)(hm + ((size_t)b * C_ + c) * HW_);
            nms_scan_channel(img, [&](float f, float m, int y, int x) {
                bool hit = (f > 0.01f && f >= m);
                unsigned bin = 0u;
                if (hit) {
                    bin = (__float_as_uint(f) >> 16) - BIN_BASE;
                    if (bin > NBINS - 1) bin = NBINS - 1;
                }
                hist_add(lh, hit, bin, lane);
            });
        }
        find_suffix_thresh(lh, seg, &T1s, &cntHiS);
        unsigned T1 = T1s, cntHi = cntHiS;

        // pass 2: collect bin>T1 keys; sub-hist bits[15:8] for bin==T1
        for (int c = 0; c < C_; c++) {
            const float4* img = (const float4*)(hm + ((size_t)b * C_ + c) * HW_);
            nms_scan_channel(img, [&](float f, float m, int y, int x) {
                if (f > 0.01f && f >= m) {
                    unsigned bits = __float_as_uint(f);
                    unsigned bin = (bits >> 16) - BIN_BASE;
                    if (bin > NBINS - 1) bin = NBINS - 1;
                    if (bin > T1) {
                        unsigned pos = atomicAdd(&cntL, 1u);
                        if (pos < SORTN) s[pos] = make_key(bits, c, y, x);
                    } else if (bin == T1) {
                        atomicAdd(&shC[(bits >> 8) & 255u], 1u);
                    }
                }
            });
        }
        __syncthreads();
        sufC[t] = shC[t];
        __syncthreads();
        for (int d = 1; d < 256; d <<= 1) {
            unsigned add = (t + d < 256) ? sufC[t + d] : 0u;
            __syncthreads();
            sufC[t] += add;
            __syncthreads();
        }
        unsigned myS = cntHi + sufC[t];
        unsigned nxS = cntHi + ((t < 255) ? sufC[t + 1] : 0u);
        if (t == 0 && myS < 100u) Us = 0u;
        if (myS >= 100u && nxS < 100u) Us = (unsigned)t;
        __syncthreads();
        unsigned U = Us;

        // pass 3: collect bin==T1 && sub>=U keys
        for (int c = 0; c < C_; c++) {
            const float4* img = (const float4*)(hm + ((size_t)b * C_ + c) * HW_);
            nms_scan_channel(img, [&](float f, float m, int y, int x) {
                if (f > 0.01f && f >= m) {
                    unsigned bits = __float_as_uint(f);
                    unsigned bin = (bits >> 16) - BIN_BASE;
                    if (bin > NBINS - 1) bin = NBINS - 1;
                    if (bin == T1 && ((bits >> 8) & 255u) >= U) {
                        unsigned pos = atomicAdd(&cntL, 1u);
                        if (pos < SORTN) s[pos] = make_key(bits, c, y, x);
                    }
                }
            });
        }
        __syncthreads();
        n2 = cntL;
    }
    if (n2 > SORTN) n2 = SORTN;

    // adaptive bitonic sort descending (0 pads sink to the bottom)
    unsigned SN = (n2 <= 256u) ? 256u : SORTN;
    for (unsigned i = n2 + t; i < SN; i += 256) s[i] = 0ull;
    __syncthreads();
    for (unsigned k = 2; k <= SN; k <<= 1) {
        for (unsigned j = k >> 1; j > 0; j >>= 1) {
            for (unsigned tt = t; tt < SN; tt += 256) {
                unsigned ixj = tt ^ j;
                if (ixj > tt) {
                    unsigned long long a = s[tt], bb = s[ixj];
                    bool desc = ((tt & k) == 0u);
                    if (desc ? (a < bb) : (a > bb)) { s[tt] = bb; s[ixj] = a; }
                }
            }
            __syncthreads();
        }
    }

    // decode + write
    int r = t;
    if (r < 100) {
        float idv, sc, b0, b1, b2, b3;
        if ((unsigned)r < n2) {
            unsigned long long key = s[r];
            unsigned bits = (unsigned)(key >> 32);
            unsigned idx  = 0xFFFFFFFFu - (unsigned)(key & 0xFFFFFFFFu);
            float v = __uint_as_float(bits);
            int c  = (int)(idx >> 14);
            int sp = (int)(idx & 16383u);
            int y  = sp >> 7;
            int x  = sp & 127;
            const float* offb = offset + (size_t)b * 2 * HW_;
            const float* whb  = wh + (size_t)b * 2 * HW_;
            float ox = offb[sp], oy = offb[HW_ + sp];
            float wwv = whb[sp], hh = whb[HW_ + sp];
            float cx = (float)x + ox;
            float cy = (float)y + oy;
            idv = (float)c;
            sc  = v;
            b0 = (cx - wwv * 0.5f) * 4.0f;
            b1 = (cy - hh * 0.5f) * 4.0f;
            b2 = (cx + wwv * 0.5f) * 4.0f;
            b3 = (cy + hh * 0.5f) * 4.0f;
        } else {
            idv = -1.0f; sc = -1.0f;
            b0 = b1 = b2 = b3 = -4.0f;   // where(keep, bbox, -1) * SCALE
        }
        int o = b * 100 + r;
        out[o]        = idv;
        out[1600 + o] = sc;
        float* bb = out + 3200 + o * 4;
        bb[0] = b0; bb[1] = b1; bb[2] = b2; bb[3] = b3;
    }
}

// ---------------------------------------------------------------------------
extern "C" void kernel_launch(void* const* d_in, const int* in_sizes, int n_in,
                              void* d_out, int out_size, void* d_ws, size_t ws_size,
                              hipStream_t stream) {
    const float* heatmap = (const float*)d_in[0];
    const float* offset  = (const float*)d_in[1];
    const float* wh      = (const float*)d_in[2];
    float* out = (float*)d_out;

    char* ws = (char*)d_ws;
    unsigned* cnt1 = (unsigned*)(ws + WS_C1_OFF);
    unsigned long long* buf = (unsigned long long*)(ws + WS_BUF_OFF);

    hipMemsetAsync(d_ws, 0, WS_ZERO_BYTES, stream);

    nms_eager<<<dim3(B_ * C_), dim3(256), 0, stream>>>(heatmap, cnt1, buf);
    topk_decode<<<dim3(B_), dim3(256), 0, stream>>>(heatmap, buf, cnt1, offset, wh, out);
}